// Round 5
// baseline (3270.898 us; speedup 1.0000x reference)
//
#include <hip/hip_runtime.h>

#define N_NODES 100000
#define N_EDGES 3200000
#define D 64
#define EPS 1e-5f
#define SCAN_CHUNK 1024
#define NB_SCAN ((N_NODES + SCAN_CHUNK - 1) / SCAN_CHUNK)   // 98

#define BSHIFT 7
#define BNODES 128                                          // nodes per bucket
#define NBUCK ((N_NODES + BNODES - 1) / BNODES)             // 782
#define BCUR_STRIDE 16                                      // pad counters to one line
#define P1_CHUNK 8192
#define NB_P1 ((N_EDGES + P1_CHUNK - 1) / P1_CHUNK)         // 391
#define SRC_MASK 0x1FFFFu                                   // 17 bits >= 100000

__device__ __forceinline__ float bf2f(unsigned short h) {
  return __uint_as_float(((unsigned int)h) << 16);
}
__device__ __forceinline__ unsigned short f2bf(float f) {
  unsigned int u = __float_as_uint(f);
  u += 0x7FFFu + ((u >> 16) & 1u);          // round to nearest even
  return (unsigned short)(u >> 16);
}

// ---------------------------------------------------------------------------
// Fold GCNConv weight + FC weight into one 64x64:  Wc = W @ fw,  bc = b@fw+fb
// ---------------------------------------------------------------------------
__global__ __launch_bounds__(256) void combine_weights(
    const float* __restrict__ W1, const float* __restrict__ b1,
    const float* __restrict__ fw1, const float* __restrict__ fb1,
    const float* __restrict__ W2, const float* __restrict__ b2,
    const float* __restrict__ fw2, const float* __restrict__ fb2,
    float* __restrict__ Wc1, float* __restrict__ bc1,
    float* __restrict__ Wc2, float* __restrict__ bc2) {
  const float* W  = blockIdx.x ? W2  : W1;
  const float* fw = blockIdx.x ? fw2 : fw1;
  const float* b  = blockIdx.x ? b2  : b1;
  const float* fb = blockIdx.x ? fb2 : fb1;
  float* Wc = blockIdx.x ? Wc2 : Wc1;
  float* bc = blockIdx.x ? bc2 : bc1;

  __shared__ float sW[64 * 64];
  __shared__ float sf[64 * 64];
  for (int i = threadIdx.x; i < 4096; i += 256) { sW[i] = W[i]; sf[i] = fw[i]; }
  __syncthreads();
  for (int o = threadIdx.x; o < 4096; o += 256) {
    int i = o >> 6, j = o & 63;
    float acc = 0.f;
    #pragma unroll
    for (int k = 0; k < 64; ++k) acc += sW[i * 64 + k] * sf[k * 64 + j];
    Wc[o] = acc;
  }
  if (threadIdx.x < 64) {
    int j = threadIdx.x;
    float acc = fb[j];
    #pragma unroll
    for (int k = 0; k < 64; ++k) acc += b[k] * sf[k * 64 + j];
    bc[j] = acc;
  }
}

// zero edge-count histogram + BN stat accumulators
__global__ void zero_init(int* __restrict__ cnt, float* __restrict__ stats) {
  int i = blockIdx.x * blockDim.x + threadIdx.x;
  if (i < N_NODES) cnt[i] = 0;
  if (i < 256) stats[i] = 0.0f;
}

__global__ void hist_dst(const int* __restrict__ dst, int* __restrict__ cnt) {
  int e = blockIdx.x * blockDim.x + threadIdx.x;
  if (e < N_EDGES) atomicAdd(&cnt[dst[e]], 1);
}

// dinv[i] = rsqrt(deg) with deg = cnt + 1 (self loop)
__global__ void make_dinv(const int* __restrict__ cnt, float* __restrict__ dinv) {
  int i = blockIdx.x * blockDim.x + threadIdx.x;
  if (i < N_NODES) dinv[i] = rsqrtf((float)cnt[i] + 1.0f);
}

// Xs[i][:] = bf16( dinv[i] * x[i][:] )
__global__ void prescale_x(const float* __restrict__ x, const float* __restrict__ dinv,
                           unsigned short* __restrict__ Xs) {
  int idx = blockIdx.x * blockDim.x + threadIdx.x;
  if (idx < N_NODES * D) Xs[idx] = f2bf(dinv[idx >> 6] * x[idx]);
}

// Ys[i][:] = bf16( dinv[i] * relu(Y[i][:]*a + c) )   (fused BN-affine of layer 1)
__global__ void prescale_y(const float* __restrict__ Y, const float* __restrict__ dinv,
                           const float* __restrict__ a, const float* __restrict__ c,
                           unsigned short* __restrict__ Ys) {
  int idx = blockIdx.x * blockDim.x + threadIdx.x;
  if (idx < N_NODES * D) {
    int i = idx >> 6, j = idx & 63;
    Ys[idx] = f2bf(dinv[i] * fmaxf(fmaf(Y[idx], a[j], c[j]), 0.f));
  }
}

// ---- 3-kernel exclusive prefix sum of cnt -> off ---------------------------
__global__ __launch_bounds__(256) void scan_blocks(const int* __restrict__ cnt,
                                                   int* __restrict__ off,
                                                   int* __restrict__ bsum) {
  __shared__ int ts[256];
  const int tid = threadIdx.x;
  const int base = blockIdx.x * SCAN_CHUNK + tid * 4;
  int v[4];
  #pragma unroll
  for (int j = 0; j < 4; ++j) v[j] = (base + j < N_NODES) ? cnt[base + j] : 0;
  int run = 0;
  #pragma unroll
  for (int j = 0; j < 4; ++j) { int t = v[j]; v[j] = run; run += t; }
  ts[tid] = run;
  __syncthreads();
  for (int o = 1; o < 256; o <<= 1) {
    int add = (tid >= o) ? ts[tid - o] : 0;
    __syncthreads();
    ts[tid] += add;
    __syncthreads();
  }
  int excl = ts[tid] - run;
  #pragma unroll
  for (int j = 0; j < 4; ++j)
    if (base + j < N_NODES) off[base + j] = excl + v[j];
  if (tid == 0) bsum[blockIdx.x] = ts[255];
}

__global__ void scan_totals(int* __restrict__ bsum) {
  __shared__ int ts[128];
  const int tid = threadIdx.x;
  int v = (tid < NB_SCAN) ? bsum[tid] : 0;
  ts[tid] = v;
  __syncthreads();
  for (int o = 1; o < 128; o <<= 1) {
    int add = (tid >= o) ? ts[tid - o] : 0;
    __syncthreads();
    ts[tid] += add;
    __syncthreads();
  }
  if (tid < NB_SCAN) bsum[tid] = ts[tid] - v;
}

__global__ void add_offsets(int* __restrict__ off, const int* __restrict__ bsum) {
  int i = blockIdx.x * blockDim.x + threadIdx.x;
  if (i < N_NODES) off[i] = off[i] + bsum[i / SCAN_CHUNK];
  else if (i == N_NODES) off[N_NODES] = N_EDGES;
}

// bucket write cursors start at the bucket's base offset (padded, 1/cacheline)
__global__ void bucket_bases(const int* __restrict__ off, int* __restrict__ bcur) {
  int b = blockIdx.x * blockDim.x + threadIdx.x;
  if (b < NBUCK) bcur[b * BCUR_STRIDE] = off[b * BNODES];
}

// ---------------------------------------------------------------------------
// Pass 1: partition edges by 128-node dst-bucket into packed[] runs.
// packed = (dst & 127) << 17 | src.  Per-block LDS histogram amortizes the
// global atomics; writes land in ~contiguous per-(block,bucket) runs.
// ---------------------------------------------------------------------------
__global__ __launch_bounds__(256) void pass1_bin(
    const int* __restrict__ src, const int* __restrict__ dst,
    int* __restrict__ bcur, unsigned int* __restrict__ packed) {
  __shared__ unsigned int hist[NBUCK];
  __shared__ unsigned int base[NBUCK];
  const int tid = threadIdx.x;
  const int e0 = blockIdx.x * P1_CHUNK;

  for (int b = tid; b < NBUCK; b += 256) hist[b] = 0;
  __syncthreads();

  #pragma unroll
  for (int k = 0; k < P1_CHUNK / 256; ++k) {
    int e = e0 + k * 256 + tid;
    if (e < N_EDGES) atomicAdd(&hist[((unsigned)dst[e]) >> BSHIFT], 1u);
  }
  __syncthreads();

  for (int b = tid; b < NBUCK; b += 256) {
    unsigned int h = hist[b];
    base[b] = h ? (unsigned)atomicAdd(&bcur[b * BCUR_STRIDE], (int)h) : 0u;
    hist[b] = 0;                        // reuse as local cursor
  }
  __syncthreads();

  #pragma unroll
  for (int k = 0; k < P1_CHUNK / 256; ++k) {
    int e = e0 + k * 256 + tid;
    if (e < N_EDGES) {
      int t = dst[e];
      int b = ((unsigned)t) >> BSHIFT;
      unsigned int pos = base[b] + atomicAdd(&hist[b], 1u);
      packed[pos] = (((unsigned)(t & (BNODES - 1))) << 17) | (unsigned)src[e];
    }
  }
}

// ---------------------------------------------------------------------------
// Aggregation: one block per bucket, 128x64 fp32 accumulator tile in LDS.
// Each wave broadcasts packed edges via shfl, gathers bf16 rows, ds_add_f32.
//   agg[t] = dinv[t] * ( Xs[t] + sum_{s in N(t)} Xs[s] )
// ---------------------------------------------------------------------------
__global__ __launch_bounds__(512) void agg_bin(
    const int* __restrict__ off, const unsigned int* __restrict__ packed,
    const unsigned short* __restrict__ Xs, const float* __restrict__ dinv,
    float* __restrict__ agg) {
  __shared__ float acc[BNODES * D];     // 32 KB -> 4 blocks/CU
  const int tid  = threadIdx.x;
  const int lane = tid & 63;
  const int wv   = tid >> 6;            // 0..7
  const int n0   = blockIdx.x * BNODES;
  const int nn   = min(BNODES, N_NODES - n0);

  // init: self-loop term (already prescaled by dinv[t])
  for (int r = wv; r < BNODES; r += 8)
    acc[r * D + lane] = (r < nn) ? bf2f(Xs[(n0 + r) * D + lane]) : 0.f;
  __syncthreads();

  const int es = off[n0];
  const int ee = off[min(n0 + BNODES, N_NODES)];

  for (int g = es + wv * 64; g < ee; g += 8 * 64) {
    const int cnt = min(64, ee - g);
    const int my = packed[g + min(lane, cnt - 1)];
    int j = 0;
    for (; j + 8 <= cnt; j += 8) {
      unsigned int p0 = (unsigned)__shfl(my, j);
      unsigned int p1 = (unsigned)__shfl(my, j + 1);
      unsigned int p2 = (unsigned)__shfl(my, j + 2);
      unsigned int p3 = (unsigned)__shfl(my, j + 3);
      unsigned int p4 = (unsigned)__shfl(my, j + 4);
      unsigned int p5 = (unsigned)__shfl(my, j + 5);
      unsigned int p6 = (unsigned)__shfl(my, j + 6);
      unsigned int p7 = (unsigned)__shfl(my, j + 7);
      float v0 = bf2f(Xs[(p0 & SRC_MASK) * D + lane]);
      float v1 = bf2f(Xs[(p1 & SRC_MASK) * D + lane]);
      float v2 = bf2f(Xs[(p2 & SRC_MASK) * D + lane]);
      float v3 = bf2f(Xs[(p3 & SRC_MASK) * D + lane]);
      float v4 = bf2f(Xs[(p4 & SRC_MASK) * D + lane]);
      float v5 = bf2f(Xs[(p5 & SRC_MASK) * D + lane]);
      float v6 = bf2f(Xs[(p6 & SRC_MASK) * D + lane]);
      float v7 = bf2f(Xs[(p7 & SRC_MASK) * D + lane]);
      atomicAdd(&acc[(p0 >> 17) * D + lane], v0);
      atomicAdd(&acc[(p1 >> 17) * D + lane], v1);
      atomicAdd(&acc[(p2 >> 17) * D + lane], v2);
      atomicAdd(&acc[(p3 >> 17) * D + lane], v3);
      atomicAdd(&acc[(p4 >> 17) * D + lane], v4);
      atomicAdd(&acc[(p5 >> 17) * D + lane], v5);
      atomicAdd(&acc[(p6 >> 17) * D + lane], v6);
      atomicAdd(&acc[(p7 >> 17) * D + lane], v7);
    }
    for (; j < cnt; ++j) {
      unsigned int p = (unsigned)__shfl(my, j);
      atomicAdd(&acc[(p >> 17) * D + lane], bf2f(Xs[(p & SRC_MASK) * D + lane]));
    }
  }
  __syncthreads();

  for (int r = wv; r < nn; r += 8)
    agg[(n0 + r) * D + lane] = dinv[n0 + r] * acc[r * D + lane];
}

// ---------------------------------------------------------------------------
// Y[64-row tile] = A @ Wc + bc, fused per-column sum / sum-of-squares partials
// ---------------------------------------------------------------------------
__global__ __launch_bounds__(256) void gemm_stats(
    const float* __restrict__ A, const float* __restrict__ Wc,
    const float* __restrict__ bc, float* __restrict__ Y,
    float* __restrict__ colsum, float* __restrict__ colsq) {
  __shared__ float sA[64 * 64];
  __shared__ float sW[64 * 64];
  __shared__ float sB[64];
  __shared__ float red[8][64];

  const int tid = threadIdx.x;
  const int c = tid & 63;
  const int rg = tid >> 6;
  const int rowBase = blockIdx.x * 64;

  for (int i = tid; i < 4096; i += 256) {
    int r = rowBase + (i >> 6);
    sA[i] = (r < N_NODES) ? A[r * 64 + (i & 63)] : 0.0f;
    sW[i] = Wc[i];
  }
  if (tid < 64) sB[tid] = bc[tid];
  __syncthreads();

  float acc[16];
  #pragma unroll
  for (int rr = 0; rr < 16; ++rr) acc[rr] = 0.f;
  const int rA = rg * 16;
  for (int k = 0; k < 64; ++k) {
    float w = sW[k * 64 + c];
    #pragma unroll
    for (int rr = 0; rr < 16; ++rr)
      acc[rr] += sA[(rA + rr) * 64 + k] * w;
  }

  float psum = 0.f, psq = 0.f;
  #pragma unroll
  for (int rr = 0; rr < 16; ++rr) {
    int r = rowBase + rA + rr;
    if (r < N_NODES) {
      float y = acc[rr] + sB[c];
      Y[r * 64 + c] = y;
      psum += y;
      psq += y * y;
    }
  }
  red[rg][c] = psum;
  red[rg + 4][c] = psq;
  __syncthreads();
  if (tid < 64) {
    float s = red[0][c] + red[1][c] + red[2][c] + red[3][c];
    float q = red[4][c] + red[5][c] + red[6][c] + red[7][c];
    atomicAdd(&colsum[c], s);
    atomicAdd(&colsq[c], q);
  }
}

__global__ void finalize_stats(const float* __restrict__ colsum, const float* __restrict__ colsq,
                               const float* __restrict__ g, const float* __restrict__ bt,
                               float* __restrict__ a, float* __restrict__ c) {
  int j = threadIdx.x;
  if (j < 64) {
    float mu = colsum[j] * (1.0f / N_NODES);
    float var = colsq[j] * (1.0f / N_NODES) - mu * mu;
    float s = rsqrtf(var + EPS) * g[j];
    a[j] = s;
    c[j] = bt[j] - mu * s;
  }
}

__global__ void final_norm(float* __restrict__ Y, const float* __restrict__ a,
                           const float* __restrict__ c) {
  int idx = blockIdx.x * blockDim.x + threadIdx.x;
  if (idx < N_NODES * D) {
    int j = idx & 63;
    Y[idx] = fmaxf(fmaf(Y[idx], a[j], c[j]), 0.f);
  }
}

extern "C" void kernel_launch(void* const* d_in, const int* in_sizes, int n_in,
                              void* d_out, int out_size, void* d_ws, size_t ws_size,
                              hipStream_t stream) {
  const float* x   = (const float*)d_in[0];
  const int*   src = (const int*)d_in[1];          // edge_index row 0
  const int*   dst = src + N_EDGES;                // edge_index row 1
  const float* W1  = (const float*)d_in[2];
  const float* b1  = (const float*)d_in[3];
  const float* fw1 = (const float*)d_in[4];
  const float* fb1 = (const float*)d_in[5];
  const float* g1  = (const float*)d_in[6];
  const float* bt1 = (const float*)d_in[7];
  const float* W2  = (const float*)d_in[8];
  const float* b2  = (const float*)d_in[9];
  const float* fw2 = (const float*)d_in[10];
  const float* fb2 = (const float*)d_in[11];
  const float* g2  = (const float*)d_in[12];
  const float* bt2 = (const float*)d_in[13];

  float* Y = (float*)d_out;                        // N x 64, reused y1 -> y2 -> out

  // workspace layout (~52.5 MB)
  float*          ws     = (float*)d_ws;
  float*          agg    = ws;                                 // N*64 floats
  float*          dinv   = agg + (size_t)N_NODES * D;          // N floats
  unsigned short* Xs     = (unsigned short*)(dinv + N_NODES);  // N*64 ushort
  unsigned int*   packed = (unsigned int*)(Xs + (size_t)N_NODES * D); // E uints
  int*   cnt  = (int*)(packed + N_EDGES);          // N ints
  int*   off  = cnt + N_NODES;                     // N+1 ints
  int*   bcur = off + N_NODES + 1;                 // NBUCK*BCUR_STRIDE ints
  int*   bsum = bcur + NBUCK * BCUR_STRIDE;        // 128 ints
  float* Wc1  = (float*)(bsum + 128);              // 4096
  float* bc1  = Wc1 + 4096;                        // 64
  float* Wc2  = bc1 + 64;                          // 4096
  float* bc2  = Wc2 + 4096;                        // 64
  float* sum1 = bc2 + 64;                          // 64  (sum1..sq2 contiguous 256)
  float* sq1  = sum1 + 64;
  float* sum2 = sq1 + 64;
  float* sq2  = sum2 + 64;
  float* a1   = sq2 + 64;
  float* c1   = a1 + 64;
  float* a2   = c1 + 64;
  float* c2   = a2 + 64;

  const int nd = N_NODES * D;
  dim3 blk(256);

  combine_weights<<<2, blk, 0, stream>>>(W1, b1, fw1, fb1, W2, b2, fw2, fb2,
                                         Wc1, bc1, Wc2, bc2);

  // ---- bucket-partition build (shared by both layers) ----
  zero_init<<<(N_NODES + 255) / 256, blk, 0, stream>>>(cnt, sum1);
  hist_dst<<<(N_EDGES + 255) / 256, blk, 0, stream>>>(dst, cnt);
  make_dinv<<<(N_NODES + 255) / 256, blk, 0, stream>>>(cnt, dinv);
  prescale_x<<<(nd + 255) / 256, blk, 0, stream>>>(x, dinv, Xs);
  scan_blocks<<<NB_SCAN, blk, 0, stream>>>(cnt, off, bsum);
  scan_totals<<<1, 128, 0, stream>>>(bsum);
  add_offsets<<<(N_NODES + 1 + 255) / 256, blk, 0, stream>>>(off, bsum);
  bucket_bases<<<(NBUCK + 255) / 256, blk, 0, stream>>>(off, bcur);
  pass1_bin<<<NB_P1, blk, 0, stream>>>(src, dst, bcur, packed);

  // ---- layer 1 ----
  agg_bin<<<NBUCK, 512, 0, stream>>>(off, packed, Xs, dinv, agg);
  gemm_stats<<<(N_NODES + 63) / 64, blk, 0, stream>>>(agg, Wc1, bc1, Y, sum1, sq1);
  finalize_stats<<<1, 64, 0, stream>>>(sum1, sq1, g1, bt1, a1, c1);

  // ---- layer 2 (BN-affine+ReLU of layer 1 fused into the prescale) ----
  prescale_y<<<(nd + 255) / 256, blk, 0, stream>>>(Y, dinv, a1, c1, Xs);
  agg_bin<<<NBUCK, 512, 0, stream>>>(off, packed, Xs, dinv, agg);
  gemm_stats<<<(N_NODES + 63) / 64, blk, 0, stream>>>(agg, Wc2, bc2, Y, sum2, sq2);
  finalize_stats<<<1, 64, 0, stream>>>(sum2, sq2, g2, bt2, a2, c2);

  final_norm<<<(nd + 255) / 256, blk, 0, stream>>>(Y, a2, c2);
}

// Round 6
// 493.767 us; speedup vs baseline: 6.6244x; 6.6244x over previous
//
#include <hip/hip_runtime.h>

#define N_NODES 100000
#define N_EDGES 3200000
#define D 64
#define EPS 1e-5f

#define BSHIFT 7
#define BNODES 128                                          // nodes per bucket
#define NBUCK ((N_NODES + BNODES - 1) / BNODES)             // 782
#define BCUR_STRIDE 16                                      // pad cursors to one line
#define P1_CHUNK 8192
#define NB_P1 ((N_EDGES + P1_CHUNK - 1) / P1_CHUNK)         // 391
#define SRC_MASK 0x1FFFFu                                   // 17 bits >= 100000
#define BCAP 6144                                           // bucket cap (mean 4092, sigma 64)

__device__ __forceinline__ unsigned short f2bf(float f) {
  unsigned int u = __float_as_uint(f);
  u += 0x7FFFu + ((u >> 16) & 1u);          // round to nearest even
  return (unsigned short)(u >> 16);
}
__device__ __forceinline__ float bf2f(unsigned short h) {
  return __uint_as_float(((unsigned int)h) << 16);
}
// add 8 bf16 (packed in uint4) into 8 fp32 accumulators
__device__ __forceinline__ void addu4(float acc[8], uint4 u) {
  acc[0] += __uint_as_float(u.x << 16);
  acc[1] += __uint_as_float(u.x & 0xFFFF0000u);
  acc[2] += __uint_as_float(u.y << 16);
  acc[3] += __uint_as_float(u.y & 0xFFFF0000u);
  acc[4] += __uint_as_float(u.z << 16);
  acc[5] += __uint_as_float(u.z & 0xFFFF0000u);
  acc[6] += __uint_as_float(u.w << 16);
  acc[7] += __uint_as_float(u.w & 0xFFFF0000u);
}

// ---------------------------------------------------------------------------
// Fold GCNConv weight + FC weight into one 64x64:  Wc = W @ fw,  bc = b@fw+fb
// ---------------------------------------------------------------------------
__global__ __launch_bounds__(256) void combine_weights(
    const float* __restrict__ W1, const float* __restrict__ b1,
    const float* __restrict__ fw1, const float* __restrict__ fb1,
    const float* __restrict__ W2, const float* __restrict__ b2,
    const float* __restrict__ fw2, const float* __restrict__ fb2,
    float* __restrict__ Wc1, float* __restrict__ bc1,
    float* __restrict__ Wc2, float* __restrict__ bc2) {
  const float* W  = blockIdx.x ? W2  : W1;
  const float* fw = blockIdx.x ? fw2 : fw1;
  const float* b  = blockIdx.x ? b2  : b1;
  const float* fb = blockIdx.x ? fb2 : fb1;
  float* Wc = blockIdx.x ? Wc2 : Wc1;
  float* bc = blockIdx.x ? bc2 : bc1;

  __shared__ float sW[64 * 64];
  __shared__ float sf[64 * 64];
  for (int i = threadIdx.x; i < 4096; i += 256) { sW[i] = W[i]; sf[i] = fw[i]; }
  __syncthreads();
  for (int o = threadIdx.x; o < 4096; o += 256) {
    int i = o >> 6, j = o & 63;
    float acc = 0.f;
    #pragma unroll
    for (int k = 0; k < 64; ++k) acc += sW[i * 64 + k] * sf[k * 64 + j];
    Wc[o] = acc;
  }
  if (threadIdx.x < 64) {
    int j = threadIdx.x;
    float acc = fb[j];
    #pragma unroll
    for (int k = 0; k < 64; ++k) acc += b[k] * sf[k * 64 + j];
    bc[j] = acc;
  }
}

// zero bucket counts + BN stat accumulators
__global__ void zero_misc(int* __restrict__ bcnt, float* __restrict__ stats) {
  int i = blockIdx.x * blockDim.x + threadIdx.x;
  if (i < NBUCK) bcnt[i] = 0;
  if (i < 256) stats[i] = 0.0f;
}

// ---- pass 1a: per-bucket edge counts (LDS histogram, int atomics only) -----
__global__ __launch_bounds__(256) void p1_hist(const int* __restrict__ dst,
                                               int* __restrict__ bcnt) {
  __shared__ unsigned int h[NBUCK];
  const int tid = threadIdx.x;
  const int e0 = blockIdx.x * P1_CHUNK;
  for (int b = tid; b < NBUCK; b += 256) h[b] = 0;
  __syncthreads();
  #pragma unroll
  for (int k = 0; k < P1_CHUNK / 256; ++k) {
    int e = e0 + k * 256 + tid;
    if (e < N_EDGES) atomicAdd(&h[((unsigned)dst[e]) >> BSHIFT], 1u);
  }
  __syncthreads();
  for (int b = tid; b < NBUCK; b += 256)
    if (h[b]) atomicAdd((unsigned int*)&bcnt[b], h[b]);
}

// ---- exclusive scan of 782 bucket counts -> bbase, init bcur ----------------
__global__ __launch_bounds__(256) void bucket_scan(const int* __restrict__ bcnt,
                                                   int* __restrict__ bbase,
                                                   int* __restrict__ bcur) {
  __shared__ int ts[256];
  const int tid = threadIdx.x;
  const int base = tid * 4;
  int v[4];
  #pragma unroll
  for (int j = 0; j < 4; ++j) v[j] = (base + j < NBUCK) ? bcnt[base + j] : 0;
  int run = 0;
  #pragma unroll
  for (int j = 0; j < 4; ++j) { int t = v[j]; v[j] = run; run += t; }
  ts[tid] = run;
  __syncthreads();
  for (int o = 1; o < 256; o <<= 1) {
    int add = (tid >= o) ? ts[tid - o] : 0;
    __syncthreads();
    ts[tid] += add;
    __syncthreads();
  }
  int excl = ts[tid] - run;
  #pragma unroll
  for (int j = 0; j < 4; ++j)
    if (base + j < NBUCK) {
      int o = excl + v[j];
      bbase[base + j] = o;
      bcur[(base + j) * BCUR_STRIDE] = o;
    }
  if (tid == 0) bbase[NBUCK] = N_EDGES;
}

// ---- pass 1b: partition edges into bucket runs of packed = dstLow<<17|src --
__global__ __launch_bounds__(256) void pass1b(
    const int* __restrict__ src, const int* __restrict__ dst,
    int* __restrict__ bcur, unsigned int* __restrict__ packed) {
  __shared__ unsigned int hist[NBUCK];
  __shared__ unsigned int base[NBUCK];
  const int tid = threadIdx.x;
  const int e0 = blockIdx.x * P1_CHUNK;

  for (int b = tid; b < NBUCK; b += 256) hist[b] = 0;
  __syncthreads();
  #pragma unroll
  for (int k = 0; k < P1_CHUNK / 256; ++k) {
    int e = e0 + k * 256 + tid;
    if (e < N_EDGES) atomicAdd(&hist[((unsigned)dst[e]) >> BSHIFT], 1u);
  }
  __syncthreads();
  for (int b = tid; b < NBUCK; b += 256) {
    unsigned int h = hist[b];
    base[b] = h ? (unsigned)atomicAdd(&bcur[b * BCUR_STRIDE], (int)h) : 0u;
    hist[b] = 0;                        // reuse as local cursor
  }
  __syncthreads();
  #pragma unroll
  for (int k = 0; k < P1_CHUNK / 256; ++k) {
    int e = e0 + k * 256 + tid;
    if (e < N_EDGES) {
      int t = dst[e];
      int b = ((unsigned)t) >> BSHIFT;
      unsigned int pos = base[b] + atomicAdd(&hist[b], 1u);
      packed[pos] = (((unsigned)(t & (BNODES - 1))) << 17) | (unsigned)src[e];
    }
  }
}

// ---- pass 2: per-bucket counting sort -> node CSR (in place over packed),
//      plus off[] and dinv[] (replaces hist_dst + node scan + make_dinv) ------
__global__ __launch_bounds__(256) void pass2_sort(
    unsigned int* __restrict__ packed, const int* __restrict__ bbase,
    int* __restrict__ off, float* __restrict__ dinv) {
  __shared__ int hist[BNODES];
  __shared__ int ts[BNODES];
  __shared__ int sorted[BCAP];
  const int b = blockIdx.x, tid = threadIdx.x;
  const int n0 = b * BNODES;
  const int es = bbase[b], ee = bbase[b + 1], m = ee - es;

  if (tid < BNODES) hist[tid] = 0;
  __syncthreads();
  for (int i = tid; i < m; i += 256) atomicAdd(&hist[packed[es + i] >> 17], 1);
  __syncthreads();

  int v = 0;
  if (tid < BNODES) { v = hist[tid]; ts[tid] = v; }
  __syncthreads();
  for (int o = 1; o < BNODES; o <<= 1) {
    int add = (tid >= o && tid < BNODES) ? ts[tid - o] : 0;
    __syncthreads();
    if (tid < BNODES) ts[tid] += add;
    __syncthreads();
  }
  if (tid < BNODES) {
    int excl = ts[tid] - v;
    int node = n0 + tid;
    if (node < N_NODES) {
      off[node] = es + excl;
      dinv[node] = rsqrtf((float)v + 1.0f);
    }
    hist[tid] = excl;                   // reuse as cursor
  }
  if (b == 0 && tid == 0) off[N_NODES] = N_EDGES;
  __syncthreads();

  for (int i = tid; i < m; i += 256) {
    unsigned int p = packed[es + i];
    int pos = atomicAdd(&hist[p >> 17], 1);
    if (pos < BCAP) sorted[pos] = (int)(p & SRC_MASK);
  }
  __syncthreads();
  for (int i = tid; i < m; i += 256) ((int*)packed)[es + i] = sorted[i];
}

// Xs[i][:] = bf16( dinv[i] * x[i][:] )
__global__ void prescale_x(const float* __restrict__ x, const float* __restrict__ dinv,
                           unsigned short* __restrict__ Xs) {
  int idx = blockIdx.x * blockDim.x + threadIdx.x;
  if (idx < N_NODES * D) Xs[idx] = f2bf(dinv[idx >> 6] * x[idx]);
}

// Ys[i][:] = bf16( dinv[i] * relu(Y[i][:]*a + c) )
__global__ void prescale_y(const float* __restrict__ Y, const float* __restrict__ dinv,
                           const float* __restrict__ a, const float* __restrict__ c,
                           unsigned short* __restrict__ Ys) {
  int idx = blockIdx.x * blockDim.x + threadIdx.x;
  if (idx < N_NODES * D) {
    int i = idx >> 6, j = idx & 63;
    Ys[idx] = f2bf(dinv[i] * fmaxf(fmaf(Y[idx], a[j], c[j]), 0.f));
  }
}

// ---------------------------------------------------------------------------
// CSR aggregation: one wave per node. 8 edges per uint4 gather instruction:
// lane = (grp = edge-in-batch, sub = 16B chunk). Register acc, shfl reduce.
//   agg[t] = dinv[t] * ( Xs[t] + sum_{s in N(t)} Xs[s] )
// ---------------------------------------------------------------------------
__global__ __launch_bounds__(256) void agg_csr(
    const int* __restrict__ off, const int* __restrict__ eSrc,
    const unsigned short* __restrict__ Xs, const float* __restrict__ dinv,
    float* __restrict__ agg) {
  const int wid = (blockIdx.x * 256 + threadIdx.x) >> 6;
  const int lane = threadIdx.x & 63;
  const int grp = lane >> 3, sub = lane & 7;
  if (wid >= N_NODES) return;
  const int s0 = off[wid], s1 = off[wid + 1];
  const uint4* XsV = (const uint4*)Xs;       // row r, chunk c at r*8 + c

  float acc[8];
  {
    uint4 u = XsV[(size_t)wid * 8 + sub];    // self loop: only grp 0 adds it
    if (grp != 0) { u.x = 0; u.y = 0; u.z = 0; u.w = 0; }
    acc[0] = __uint_as_float(u.x << 16);
    acc[1] = __uint_as_float(u.x & 0xFFFF0000u);
    acc[2] = __uint_as_float(u.y << 16);
    acc[3] = __uint_as_float(u.y & 0xFFFF0000u);
    acc[4] = __uint_as_float(u.z << 16);
    acc[5] = __uint_as_float(u.z & 0xFFFF0000u);
    acc[6] = __uint_as_float(u.w << 16);
    acc[7] = __uint_as_float(u.w & 0xFFFF0000u);
  }

  int e = s0;
  for (; e + 32 <= s1; e += 32) {            // 4 gathers in flight
    int sa = eSrc[e + grp];
    int sb = eSrc[e + 8 + grp];
    int sc = eSrc[e + 16 + grp];
    int sd = eSrc[e + 24 + grp];
    uint4 ua = XsV[(size_t)sa * 8 + sub];
    uint4 ub = XsV[(size_t)sb * 8 + sub];
    uint4 uc = XsV[(size_t)sc * 8 + sub];
    uint4 ud = XsV[(size_t)sd * 8 + sub];
    addu4(acc, ua); addu4(acc, ub); addu4(acc, uc); addu4(acc, ud);
  }
  for (; e + 8 <= s1; e += 8) {
    int s = eSrc[e + grp];
    uint4 u = XsV[(size_t)s * 8 + sub];
    addu4(acc, u);
  }
  int rem = s1 - e;
  if (rem > 0) {
    int s = eSrc[e + (grp < rem ? grp : rem - 1)];
    uint4 u = XsV[(size_t)s * 8 + sub];
    if (grp >= rem) { u.x = 0; u.y = 0; u.z = 0; u.w = 0; }
    addu4(acc, u);
  }

  #pragma unroll
  for (int m = 8; m <= 32; m <<= 1) {
    #pragma unroll
    for (int i = 0; i < 8; ++i) acc[i] += __shfl_xor(acc[i], m, 64);
  }

  if (grp == 0) {
    float dt = dinv[wid];
    float4 o0, o1;
    o0.x = acc[0] * dt; o0.y = acc[1] * dt; o0.z = acc[2] * dt; o0.w = acc[3] * dt;
    o1.x = acc[4] * dt; o1.y = acc[5] * dt; o1.z = acc[6] * dt; o1.w = acc[7] * dt;
    float4* op = (float4*)(agg + (size_t)wid * 64 + sub * 8);
    op[0] = o0;
    op[1] = o1;
  }
}

// ---------------------------------------------------------------------------
// Y[64-row tile] = A @ Wc + bc, fused per-column sum / sum-of-squares partials
// ---------------------------------------------------------------------------
__global__ __launch_bounds__(256) void gemm_stats(
    const float* __restrict__ A, const float* __restrict__ Wc,
    const float* __restrict__ bc, float* __restrict__ Y,
    float* __restrict__ colsum, float* __restrict__ colsq) {
  __shared__ float sA[64 * 64];
  __shared__ float sW[64 * 64];
  __shared__ float sB[64];
  __shared__ float red[8][64];

  const int tid = threadIdx.x;
  const int c = tid & 63;
  const int rg = tid >> 6;
  const int rowBase = blockIdx.x * 64;

  for (int i = tid; i < 4096; i += 256) {
    int r = rowBase + (i >> 6);
    sA[i] = (r < N_NODES) ? A[r * 64 + (i & 63)] : 0.0f;
    sW[i] = Wc[i];
  }
  if (tid < 64) sB[tid] = bc[tid];
  __syncthreads();

  float acc[16];
  #pragma unroll
  for (int rr = 0; rr < 16; ++rr) acc[rr] = 0.f;
  const int rA = rg * 16;
  for (int k = 0; k < 64; ++k) {
    float w = sW[k * 64 + c];
    #pragma unroll
    for (int rr = 0; rr < 16; ++rr)
      acc[rr] += sA[(rA + rr) * 64 + k] * w;
  }

  float psum = 0.f, psq = 0.f;
  #pragma unroll
  for (int rr = 0; rr < 16; ++rr) {
    int r = rowBase + rA + rr;
    if (r < N_NODES) {
      float y = acc[rr] + sB[c];
      Y[r * 64 + c] = y;
      psum += y;
      psq += y * y;
    }
  }
  red[rg][c] = psum;
  red[rg + 4][c] = psq;
  __syncthreads();
  if (tid < 64) {
    float s = red[0][c] + red[1][c] + red[2][c] + red[3][c];
    float q = red[4][c] + red[5][c] + red[6][c] + red[7][c];
    atomicAdd(&colsum[c], s);
    atomicAdd(&colsq[c], q);
  }
}

__global__ void finalize_stats(const float* __restrict__ colsum, const float* __restrict__ colsq,
                               const float* __restrict__ g, const float* __restrict__ bt,
                               float* __restrict__ a, float* __restrict__ c) {
  int j = threadIdx.x;
  if (j < 64) {
    float mu = colsum[j] * (1.0f / N_NODES);
    float var = colsq[j] * (1.0f / N_NODES) - mu * mu;
    float s = rsqrtf(var + EPS) * g[j];
    a[j] = s;
    c[j] = bt[j] - mu * s;
  }
}

__global__ void final_norm(float* __restrict__ Y, const float* __restrict__ a,
                           const float* __restrict__ c) {
  int idx = blockIdx.x * blockDim.x + threadIdx.x;
  if (idx < N_NODES * D) {
    int j = idx & 63;
    Y[idx] = fmaxf(fmaf(Y[idx], a[j], c[j]), 0.f);
  }
}

extern "C" void kernel_launch(void* const* d_in, const int* in_sizes, int n_in,
                              void* d_out, int out_size, void* d_ws, size_t ws_size,
                              hipStream_t stream) {
  const float* x   = (const float*)d_in[0];
  const int*   src = (const int*)d_in[1];          // edge_index row 0
  const int*   dst = src + N_EDGES;                // edge_index row 1
  const float* W1  = (const float*)d_in[2];
  const float* b1  = (const float*)d_in[3];
  const float* fw1 = (const float*)d_in[4];
  const float* fb1 = (const float*)d_in[5];
  const float* g1  = (const float*)d_in[6];
  const float* bt1 = (const float*)d_in[7];
  const float* W2  = (const float*)d_in[8];
  const float* b2  = (const float*)d_in[9];
  const float* fw2 = (const float*)d_in[10];
  const float* fb2 = (const float*)d_in[11];
  const float* g2  = (const float*)d_in[12];
  const float* bt2 = (const float*)d_in[13];

  float* Y = (float*)d_out;                        // N x 64, reused y1 -> y2 -> out

  // workspace layout (~52.2 MB)
  float*          ws     = (float*)d_ws;
  float*          agg    = ws;                                 // N*64 floats
  float*          dinv   = agg + (size_t)N_NODES * D;          // N floats
  unsigned short* Xs     = (unsigned short*)(dinv + N_NODES);  // N*64 ushort (16B-aligned)
  unsigned int*   packed = (unsigned int*)(Xs + (size_t)N_NODES * D); // E uints; becomes eSrc
  int*   off   = (int*)(packed + N_EDGES);         // N+1 ints
  int*   bcnt  = off + N_NODES + 1;                // NBUCK ints
  int*   bbase = bcnt + NBUCK;                     // NBUCK+1 ints
  int*   bcur  = bbase + NBUCK + 1;                // NBUCK*BCUR_STRIDE ints
  float* Wc1   = (float*)(bcur + NBUCK * BCUR_STRIDE); // 4096
  float* bc1   = Wc1 + 4096;                       // 64
  float* Wc2   = bc1 + 64;                         // 4096
  float* bc2   = Wc2 + 4096;                       // 64
  float* sum1  = bc2 + 64;                         // 64  (sum1..sq2 contiguous 256)
  float* sq1   = sum1 + 64;
  float* sum2  = sq1 + 64;
  float* sq2   = sum2 + 64;
  float* a1    = sq2 + 64;
  float* c1    = a1 + 64;
  float* a2    = c1 + 64;
  float* c2    = a2 + 64;
  int*   eSrc  = (int*)packed;                     // alias after pass2_sort

  const int nd = N_NODES * D;
  dim3 blk(256);

  combine_weights<<<2, blk, 0, stream>>>(W1, b1, fw1, fb1, W2, b2, fw2, fb2,
                                         Wc1, bc1, Wc2, bc2);

  // ---- edge partition + per-bucket counting sort -> node CSR ----
  zero_misc<<<(NBUCK + 255) / 256, blk, 0, stream>>>(bcnt, sum1);
  p1_hist<<<NB_P1, blk, 0, stream>>>(dst, bcnt);
  bucket_scan<<<1, blk, 0, stream>>>(bcnt, bbase, bcur);
  pass1b<<<NB_P1, blk, 0, stream>>>(src, dst, bcur, packed);
  pass2_sort<<<NBUCK, blk, 0, stream>>>(packed, bbase, off, dinv);

  // ---- layer 1 ----
  prescale_x<<<(nd + 255) / 256, blk, 0, stream>>>(x, dinv, Xs);
  agg_csr<<<(nd + 255) / 256, blk, 0, stream>>>(off, eSrc, Xs, dinv, agg);
  gemm_stats<<<(N_NODES + 63) / 64, blk, 0, stream>>>(agg, Wc1, bc1, Y, sum1, sq1);
  finalize_stats<<<1, 64, 0, stream>>>(sum1, sq1, g1, bt1, a1, c1);

  // ---- layer 2 (BN-affine+ReLU of layer 1 fused into the prescale) ----
  prescale_y<<<(nd + 255) / 256, blk, 0, stream>>>(Y, dinv, a1, c1, Xs);
  agg_csr<<<(nd + 255) / 256, blk, 0, stream>>>(off, eSrc, Xs, dinv, agg);
  gemm_stats<<<(N_NODES + 63) / 64, blk, 0, stream>>>(agg, Wc2, bc2, Y, sum2, sq2);
  finalize_stats<<<1, 64, 0, stream>>>(sum2, sq2, g2, bt2, a2, c2);

  final_norm<<<(nd + 255) / 256, blk, 0, stream>>>(Y, a2, c2);
}

// Round 7
// 485.258 us; speedup vs baseline: 6.7405x; 1.0175x over previous
//
#include <hip/hip_runtime.h>

#define N_NODES 100000
#define N_EDGES 3200000
#define D 64
#define EPS 1e-5f

#define BSHIFT 7
#define BNODES 128                                          // nodes per bucket
#define NBUCK ((N_NODES + BNODES - 1) / BNODES)             // 782
#define P1_CHUNK 8192
#define NB_P1 ((N_EDGES + P1_CHUNK - 1) / P1_CHUNK)         // 391
#define SRC_MASK 0x1FFFFu                                   // 17 bits >= 100000
#define BCAP 4480                                           // bucket region cap (mean 4096, +6 sigma)
#define TBL_STRIDE 784                                      // 783 entries + pad

__device__ __forceinline__ unsigned short f2bf(float f) {
  unsigned int u = __float_as_uint(f);
  u += 0x7FFFu + ((u >> 16) & 1u);          // round to nearest even
  return (unsigned short)(u >> 16);
}
// add 8 bf16 (packed in uint4) into 8 fp32 accumulators
__device__ __forceinline__ void addu4(float acc[8], uint4 u) {
  acc[0] += __uint_as_float(u.x << 16);
  acc[1] += __uint_as_float(u.x & 0xFFFF0000u);
  acc[2] += __uint_as_float(u.y << 16);
  acc[3] += __uint_as_float(u.y & 0xFFFF0000u);
  acc[4] += __uint_as_float(u.z << 16);
  acc[5] += __uint_as_float(u.z & 0xFFFF0000u);
  acc[6] += __uint_as_float(u.w << 16);
  acc[7] += __uint_as_float(u.w & 0xFFFF0000u);
}

// ---------------------------------------------------------------------------
// Fold GCNConv weight + FC weight into one 64x64:  Wc = W @ fw,  bc = b@fw+fb
// ---------------------------------------------------------------------------
__global__ __launch_bounds__(256) void combine_weights(
    const float* __restrict__ W1, const float* __restrict__ b1,
    const float* __restrict__ fw1, const float* __restrict__ fb1,
    const float* __restrict__ W2, const float* __restrict__ b2,
    const float* __restrict__ fw2, const float* __restrict__ fb2,
    float* __restrict__ Wc1, float* __restrict__ bc1,
    float* __restrict__ Wc2, float* __restrict__ bc2) {
  const float* W  = blockIdx.x ? W2  : W1;
  const float* fw = blockIdx.x ? fw2 : fw1;
  const float* b  = blockIdx.x ? b2  : b1;
  const float* fb = blockIdx.x ? fb2 : fb1;
  float* Wc = blockIdx.x ? Wc2 : Wc1;
  float* bc = blockIdx.x ? bc2 : bc1;

  __shared__ float sW[64 * 64];
  __shared__ float sf[64 * 64];
  for (int i = threadIdx.x; i < 4096; i += 256) { sW[i] = W[i]; sf[i] = fw[i]; }
  __syncthreads();
  for (int o = threadIdx.x; o < 4096; o += 256) {
    int i = o >> 6, j = o & 63;
    float acc = 0.f;
    #pragma unroll
    for (int k = 0; k < 64; ++k) acc += sW[i * 64 + k] * sf[k * 64 + j];
    Wc[o] = acc;
  }
  if (threadIdx.x < 64) {
    int j = threadIdx.x;
    float acc = fb[j];
    #pragma unroll
    for (int k = 0; k < 64; ++k) acc += b[k] * sf[k * 64 + j];
    bc[j] = acc;
  }
}

__global__ void zero_stats(float* __restrict__ stats) {
  if (threadIdx.x < 256) stats[threadIdx.x] = 0.0f;
}

// ---------------------------------------------------------------------------
// Pass 1: block-local counting sort of an 8192-edge chunk by 128-node bucket.
// Output: stage[blk*8192 ...] coalesced (packed = dstLow<<17|src) + a 783-entry
// ushort offset-table row. No global atomics, no random writes.
// ---------------------------------------------------------------------------
__global__ __launch_bounds__(512) void pass1_sort(
    const int* __restrict__ src, const int* __restrict__ dst,
    unsigned int* __restrict__ stage, unsigned short* __restrict__ tbl) {
  __shared__ unsigned int hist[NBUCK];
  __shared__ unsigned int ts[512];
  __shared__ unsigned int sorted[P1_CHUNK];
  const int tid = threadIdx.x;
  const int e0 = blockIdx.x * P1_CHUNK;

  for (int b = tid; b < NBUCK; b += 512) hist[b] = 0;
  __syncthreads();

  int dreg[16];                               // dst cached -> no second dst read
  #pragma unroll
  for (int k = 0; k < 16; ++k) {
    int e = e0 + k * 512 + tid;
    int d = (e < N_EDGES) ? dst[e] : -1;
    dreg[k] = d;
    if (d >= 0) atomicAdd(&hist[((unsigned)d) >> BSHIFT], 1u);
  }
  __syncthreads();

  // exclusive scan of hist (thread owns buckets 2t, 2t+1)
  unsigned int v0 = (2 * tid < NBUCK) ? hist[2 * tid] : 0u;
  unsigned int v1 = (2 * tid + 1 < NBUCK) ? hist[2 * tid + 1] : 0u;
  unsigned int run = v0 + v1;
  ts[tid] = run;
  __syncthreads();
  for (int o = 1; o < 512; o <<= 1) {
    unsigned int add = (tid >= o) ? ts[tid - o] : 0u;
    __syncthreads();
    ts[tid] += add;
    __syncthreads();
  }
  const unsigned int excl = ts[tid] - run;
  const unsigned int m = ts[511];             // real edges in this chunk
  unsigned short* trow = tbl + (size_t)blockIdx.x * TBL_STRIDE;
  if (2 * tid < NBUCK)     { hist[2 * tid]     = excl;      trow[2 * tid]     = (unsigned short)excl; }
  if (2 * tid + 1 < NBUCK) { hist[2 * tid + 1] = excl + v0; trow[2 * tid + 1] = (unsigned short)(excl + v0); }
  if (tid == 0) trow[NBUCK] = (unsigned short)m;
  __syncthreads();

  #pragma unroll
  for (int k = 0; k < 16; ++k) {
    int e = e0 + k * 512 + tid;
    int t = dreg[k];
    if (t >= 0) {
      unsigned int pos = atomicAdd(&hist[((unsigned)t) >> BSHIFT], 1u);
      sorted[pos] = (((unsigned)(t & (BNODES - 1))) << 17) | (unsigned)src[e];
    }
  }
  __syncthreads();

  unsigned int* so = stage + (size_t)blockIdx.x * P1_CHUNK;
  for (int i = tid; i < (int)m; i += 512) so[i] = sorted[i];
}

// ---------------------------------------------------------------------------
// Pass 2: per-bucket gather of the 391 chunk-segments + counting sort to node
// order. Emits eSrc (bucket-padded regions), off/edeg per node, and dinv.
// ---------------------------------------------------------------------------
__global__ __launch_bounds__(512) void pass2_sort(
    const unsigned int* __restrict__ stage, const unsigned short* __restrict__ tbl,
    int* __restrict__ eSrc, int* __restrict__ off, int* __restrict__ edeg,
    float* __restrict__ dinv) {
  __shared__ int cnt[BNODES];
  __shared__ int ts[BNODES];
  __shared__ int sorted[BCAP];
  const int b = blockIdx.x, tid = threadIdx.x;
  const int lane = tid & 63, wv = tid >> 6;   // 8 waves
  const int n0 = b * BNODES;

  if (tid < BNODES) cnt[tid] = 0;
  __syncthreads();

  // pass A: histogram over this bucket's segments (L2-hot re-read later)
  for (int blk = wv; blk < NB_P1; blk += 8) {
    const unsigned short* trow = tbl + (size_t)blk * TBL_STRIDE;
    const int o0 = trow[b], o1 = trow[b + 1];
    const unsigned int* seg = stage + (size_t)blk * P1_CHUNK;
    for (int i = o0 + lane; i < o1; i += 64)
      atomicAdd(&cnt[seg[i] >> 17], 1);
  }
  __syncthreads();

  int v = 0;
  if (tid < BNODES) { v = cnt[tid]; ts[tid] = v; }
  __syncthreads();
  for (int o = 1; o < BNODES; o <<= 1) {
    int add = (tid >= o && tid < BNODES) ? ts[tid - o] : 0;
    __syncthreads();
    if (tid < BNODES) ts[tid] += add;
    __syncthreads();
  }
  const int m = ts[BNODES - 1];
  if (tid < BNODES) {
    int excl = ts[tid] - v;
    int node = n0 + tid;
    if (node < N_NODES) {
      off[node]  = b * BCAP + excl;
      edeg[node] = v;
      dinv[node] = rsqrtf((float)v + 1.0f);
    }
    cnt[tid] = excl;                          // becomes cursor
  }
  __syncthreads();

  // pass B: scatter into node order
  for (int blk = wv; blk < NB_P1; blk += 8) {
    const unsigned short* trow = tbl + (size_t)blk * TBL_STRIDE;
    const int o0 = trow[b], o1 = trow[b + 1];
    const unsigned int* seg = stage + (size_t)blk * P1_CHUNK;
    for (int i = o0 + lane; i < o1; i += 64) {
      unsigned int p = seg[i];
      int pos = atomicAdd(&cnt[p >> 17], 1);
      if (pos < BCAP) sorted[pos] = (int)(p & SRC_MASK);
    }
  }
  __syncthreads();

  int* out = eSrc + (size_t)b * BCAP;
  for (int i = tid; i < m; i += 512) out[i] = sorted[i];
}

// Xs[i][:] = bf16( dinv[i] * x[i][:] )
__global__ void prescale_x(const float* __restrict__ x, const float* __restrict__ dinv,
                           unsigned short* __restrict__ Xs) {
  int idx = blockIdx.x * blockDim.x + threadIdx.x;
  if (idx < N_NODES * D) Xs[idx] = f2bf(dinv[idx >> 6] * x[idx]);
}

// Ys[i][:] = bf16( dinv[i] * relu(Y[i][:]*a + c) )
__global__ void prescale_y(const float* __restrict__ Y, const float* __restrict__ dinv,
                           const float* __restrict__ a, const float* __restrict__ c,
                           unsigned short* __restrict__ Ys) {
  int idx = blockIdx.x * blockDim.x + threadIdx.x;
  if (idx < N_NODES * D) {
    int i = idx >> 6, j = idx & 63;
    Ys[idx] = f2bf(dinv[i] * fmaxf(fmaf(Y[idx], a[j], c[j]), 0.f));
  }
}

// ---------------------------------------------------------------------------
// CSR aggregation: one wave per node, 8 edges per uint4 gather, bf16 output.
//   agg[t] = dinv[t] * ( Xs[t] + sum_{s in N(t)} Xs[s] )
// ---------------------------------------------------------------------------
__global__ __launch_bounds__(256) void agg_csr(
    const int* __restrict__ off, const int* __restrict__ edeg,
    const int* __restrict__ eSrc, const unsigned short* __restrict__ Xs,
    const float* __restrict__ dinv, unsigned short* __restrict__ agg) {
  const int wid = (blockIdx.x * 256 + threadIdx.x) >> 6;
  const int lane = threadIdx.x & 63;
  const int grp = lane >> 3, sub = lane & 7;
  if (wid >= N_NODES) return;
  const int s0 = off[wid];
  const int s1 = s0 + edeg[wid];
  const uint4* XsV = (const uint4*)Xs;        // row r, chunk c at r*8 + c

  float acc[8];
  {
    uint4 u = XsV[(size_t)wid * 8 + sub];     // self loop: only grp 0 adds it
    if (grp != 0) { u.x = 0; u.y = 0; u.z = 0; u.w = 0; }
    acc[0] = __uint_as_float(u.x << 16);
    acc[1] = __uint_as_float(u.x & 0xFFFF0000u);
    acc[2] = __uint_as_float(u.y << 16);
    acc[3] = __uint_as_float(u.y & 0xFFFF0000u);
    acc[4] = __uint_as_float(u.z << 16);
    acc[5] = __uint_as_float(u.z & 0xFFFF0000u);
    acc[6] = __uint_as_float(u.w << 16);
    acc[7] = __uint_as_float(u.w & 0xFFFF0000u);
  }

  int e = s0;
  for (; e + 32 <= s1; e += 32) {             // 4 gathers in flight
    int sa = eSrc[e + grp];
    int sb = eSrc[e + 8 + grp];
    int sc = eSrc[e + 16 + grp];
    int sd = eSrc[e + 24 + grp];
    uint4 ua = XsV[(size_t)sa * 8 + sub];
    uint4 ub = XsV[(size_t)sb * 8 + sub];
    uint4 uc = XsV[(size_t)sc * 8 + sub];
    uint4 ud = XsV[(size_t)sd * 8 + sub];
    addu4(acc, ua); addu4(acc, ub); addu4(acc, uc); addu4(acc, ud);
  }
  for (; e + 8 <= s1; e += 8) {
    int s = eSrc[e + grp];
    uint4 u = XsV[(size_t)s * 8 + sub];
    addu4(acc, u);
  }
  int rem = s1 - e;
  if (rem > 0) {
    int s = eSrc[e + (grp < rem ? grp : rem - 1)];
    uint4 u = XsV[(size_t)s * 8 + sub];
    if (grp >= rem) { u.x = 0; u.y = 0; u.z = 0; u.w = 0; }
    addu4(acc, u);
  }

  #pragma unroll
  for (int mk = 8; mk <= 32; mk <<= 1) {
    #pragma unroll
    for (int i = 0; i < 8; ++i) acc[i] += __shfl_xor(acc[i], mk, 64);
  }

  if (grp == 0) {
    float dt = dinv[wid];
    uint4 o;
    o.x = ((unsigned)f2bf(acc[1] * dt) << 16) | f2bf(acc[0] * dt);
    o.y = ((unsigned)f2bf(acc[3] * dt) << 16) | f2bf(acc[2] * dt);
    o.z = ((unsigned)f2bf(acc[5] * dt) << 16) | f2bf(acc[4] * dt);
    o.w = ((unsigned)f2bf(acc[7] * dt) << 16) | f2bf(acc[6] * dt);
    *(uint4*)(agg + (size_t)wid * 64 + sub * 8) = o;
  }
}

// ---------------------------------------------------------------------------
// Y[64-row tile] = A(bf16) @ Wc + bc, fused per-column sum/sumsq partials
// ---------------------------------------------------------------------------
__global__ __launch_bounds__(256) void gemm_stats(
    const unsigned short* __restrict__ A, const float* __restrict__ Wc,
    const float* __restrict__ bc, float* __restrict__ Y,
    float* __restrict__ colsum, float* __restrict__ colsq) {
  __shared__ float sA[64 * 64];
  __shared__ float sW[64 * 64];
  __shared__ float sB[64];
  __shared__ float red[8][64];

  const int tid = threadIdx.x;
  const int c = tid & 63;
  const int rg = tid >> 6;
  const int rowBase = blockIdx.x * 64;

  const unsigned int* A32 = (const unsigned int*)A;   // 2 bf16 per uint, 32/row
  for (int i = tid; i < 2048; i += 256) {
    int rr = i >> 5, cc = i & 31;
    int r = rowBase + rr;
    unsigned int u = (r < N_NODES) ? A32[(size_t)r * 32 + cc] : 0u;
    sA[rr * 64 + cc * 2]     = __uint_as_float(u << 16);
    sA[rr * 64 + cc * 2 + 1] = __uint_as_float(u & 0xFFFF0000u);
  }
  for (int i = tid; i < 4096; i += 256) sW[i] = Wc[i];
  if (tid < 64) sB[tid] = bc[tid];
  __syncthreads();

  float acc[16];
  #pragma unroll
  for (int rr = 0; rr < 16; ++rr) acc[rr] = 0.f;
  const int rA = rg * 16;
  for (int k = 0; k < 64; ++k) {
    float w = sW[k * 64 + c];
    #pragma unroll
    for (int rr = 0; rr < 16; ++rr)
      acc[rr] += sA[(rA + rr) * 64 + k] * w;
  }

  float psum = 0.f, psq = 0.f;
  #pragma unroll
  for (int rr = 0; rr < 16; ++rr) {
    int r = rowBase + rA + rr;
    if (r < N_NODES) {
      float y = acc[rr] + sB[c];
      Y[r * 64 + c] = y;
      psum += y;
      psq += y * y;
    }
  }
  red[rg][c] = psum;
  red[rg + 4][c] = psq;
  __syncthreads();
  if (tid < 64) {
    float s = red[0][c] + red[1][c] + red[2][c] + red[3][c];
    float q = red[4][c] + red[5][c] + red[6][c] + red[7][c];
    atomicAdd(&colsum[c], s);
    atomicAdd(&colsq[c], q);
  }
}

__global__ void finalize_stats(const float* __restrict__ colsum, const float* __restrict__ colsq,
                               const float* __restrict__ g, const float* __restrict__ bt,
                               float* __restrict__ a, float* __restrict__ c) {
  int j = threadIdx.x;
  if (j < 64) {
    float mu = colsum[j] * (1.0f / N_NODES);
    float var = colsq[j] * (1.0f / N_NODES) - mu * mu;
    float s = rsqrtf(var + EPS) * g[j];
    a[j] = s;
    c[j] = bt[j] - mu * s;
  }
}

__global__ void final_norm(float* __restrict__ Y, const float* __restrict__ a,
                           const float* __restrict__ c) {
  int idx = blockIdx.x * blockDim.x + threadIdx.x;
  if (idx < N_NODES * D) {
    int j = idx & 63;
    Y[idx] = fmaxf(fmaf(Y[idx], a[j], c[j]), 0.f);
  }
}

extern "C" void kernel_launch(void* const* d_in, const int* in_sizes, int n_in,
                              void* d_out, int out_size, void* d_ws, size_t ws_size,
                              hipStream_t stream) {
  const float* x   = (const float*)d_in[0];
  const int*   src = (const int*)d_in[1];          // edge_index row 0
  const int*   dst = src + N_EDGES;                // edge_index row 1
  const float* W1  = (const float*)d_in[2];
  const float* b1  = (const float*)d_in[3];
  const float* fw1 = (const float*)d_in[4];
  const float* fb1 = (const float*)d_in[5];
  const float* g1  = (const float*)d_in[6];
  const float* bt1 = (const float*)d_in[7];
  const float* W2  = (const float*)d_in[8];
  const float* b2  = (const float*)d_in[9];
  const float* fw2 = (const float*)d_in[10];
  const float* fb2 = (const float*)d_in[11];
  const float* g2  = (const float*)d_in[12];
  const float* bt2 = (const float*)d_in[13];

  float* Y = (float*)d_out;                        // N x 64, reused y1 -> y2 -> out

  // workspace layout (~41.5 MB).  stage (pass1/2 only) and agg (bf16, per
  // layer) alias the same region: stage dead before first agg_csr write.
  unsigned char* w = (unsigned char*)d_ws;
  unsigned int*   stage = (unsigned int*)w;              // NB_P1*8192 uints = 12,812,288 B
  unsigned short* aggb  = (unsigned short*)w;            // N*64 bf16 = 12,800,000 B (alias)
  size_t ofs = ((size_t)NB_P1 * P1_CHUNK * 4 + 255) & ~(size_t)255;
  float*          dinv  = (float*)(w + ofs);             // N floats
  unsigned short* Xs    = (unsigned short*)(dinv + N_NODES);          // N*64 bf16
  int*            eSrc  = (int*)(Xs + (size_t)N_NODES * D);           // NBUCK*BCAP ints
  int*            off   = eSrc + (size_t)NBUCK * BCAP;   // N ints
  int*            edeg  = off + N_NODES;                 // N ints
  unsigned short* tbl   = (unsigned short*)(edeg + N_NODES);          // NB_P1*784 ushort
  float* Wc1  = (float*)(tbl + (size_t)NB_P1 * TBL_STRIDE);           // 4096
  float* bc1  = Wc1 + 4096;                        // 64
  float* Wc2  = bc1 + 64;                          // 4096
  float* bc2  = Wc2 + 4096;                        // 64
  float* sum1 = bc2 + 64;                          // 64  (sum1..sq2 contiguous 256)
  float* sq1  = sum1 + 64;
  float* sum2 = sq1 + 64;
  float* sq2  = sum2 + 64;
  float* a1   = sq2 + 64;
  float* c1   = a1 + 64;
  float* a2   = c1 + 64;
  float* c2   = a2 + 64;

  const int nd = N_NODES * D;
  dim3 blk(256);

  combine_weights<<<2, blk, 0, stream>>>(W1, b1, fw1, fb1, W2, b2, fw2, fb2,
                                         Wc1, bc1, Wc2, bc2);
  zero_stats<<<1, blk, 0, stream>>>(sum1);

  // ---- two-pass partition: block-local sort -> per-bucket node CSR ----
  pass1_sort<<<NB_P1, 512, 0, stream>>>(src, dst, stage, tbl);
  pass2_sort<<<NBUCK, 512, 0, stream>>>(stage, tbl, eSrc, off, edeg, dinv);

  // ---- layer 1 ----
  prescale_x<<<(nd + 255) / 256, blk, 0, stream>>>(x, dinv, Xs);
  agg_csr<<<(nd + 255) / 256, blk, 0, stream>>>(off, edeg, eSrc, Xs, dinv, aggb);
  gemm_stats<<<(N_NODES + 63) / 64, blk, 0, stream>>>(aggb, Wc1, bc1, Y, sum1, sq1);
  finalize_stats<<<1, 64, 0, stream>>>(sum1, sq1, g1, bt1, a1, c1);

  // ---- layer 2 (BN-affine+ReLU of layer 1 fused into the prescale) ----
  prescale_y<<<(nd + 255) / 256, blk, 0, stream>>>(Y, dinv, a1, c1, Xs);
  agg_csr<<<(nd + 255) / 256, blk, 0, stream>>>(off, edeg, eSrc, Xs, dinv, aggb);
  gemm_stats<<<(N_NODES + 63) / 64, blk, 0, stream>>>(aggb, Wc2, bc2, Y, sum2, sq2);
  finalize_stats<<<1, 64, 0, stream>>>(sum2, sq2, g2, bt2, a2, c2);

  final_norm<<<(nd + 255) / 256, blk, 0, stream>>>(Y, a2, c2);
}

// Round 8
// 437.734 us; speedup vs baseline: 7.4723x; 1.1086x over previous
//
#include <hip/hip_runtime.h>

#define N_NODES 100000
#define N_EDGES 3200000
#define D 64
#define EPS 1e-5f

#define BSHIFT 7
#define BNODES 128                                          // nodes per bucket
#define NBUCK ((N_NODES + BNODES - 1) / BNODES)             // 782
#define P1_CHUNK 8192
#define NB_P1 ((N_EDGES + P1_CHUNK - 1) / P1_CHUNK)         // 391
#define SRC_MASK 0x1FFFFu                                   // 17 bits >= 100000
#define BCAP 4480                                           // bucket region cap (mean 4092, +6 sigma)
#define TBL_STRIDE 784                                      // 783 entries + pad

__device__ __forceinline__ unsigned short f2bf(float f) {
  unsigned int u = __float_as_uint(f);
  u += 0x7FFFu + ((u >> 16) & 1u);          // round to nearest even
  return (unsigned short)(u >> 16);
}
// add 8 bf16 (packed in uint4) into 8 fp32 accumulators
__device__ __forceinline__ void addu4(float acc[8], uint4 u) {
  acc[0] += __uint_as_float(u.x << 16);
  acc[1] += __uint_as_float(u.x & 0xFFFF0000u);
  acc[2] += __uint_as_float(u.y << 16);
  acc[3] += __uint_as_float(u.y & 0xFFFF0000u);
  acc[4] += __uint_as_float(u.z << 16);
  acc[5] += __uint_as_float(u.z & 0xFFFF0000u);
  acc[6] += __uint_as_float(u.w << 16);
  acc[7] += __uint_as_float(u.w & 0xFFFF0000u);
}

// ---------------------------------------------------------------------------
// Fold GCNConv weight + FC weight into one 64x64:  Wc = W @ fw,  bc = b@fw+fb
// ---------------------------------------------------------------------------
__global__ __launch_bounds__(256) void combine_weights(
    const float* __restrict__ W1, const float* __restrict__ b1,
    const float* __restrict__ fw1, const float* __restrict__ fb1,
    const float* __restrict__ W2, const float* __restrict__ b2,
    const float* __restrict__ fw2, const float* __restrict__ fb2,
    float* __restrict__ Wc1, float* __restrict__ bc1,
    float* __restrict__ Wc2, float* __restrict__ bc2) {
  const float* W  = blockIdx.x ? W2  : W1;
  const float* fw = blockIdx.x ? fw2 : fw1;
  const float* b  = blockIdx.x ? b2  : b1;
  const float* fb = blockIdx.x ? fb2 : fb1;
  float* Wc = blockIdx.x ? Wc2 : Wc1;
  float* bc = blockIdx.x ? bc2 : bc1;

  __shared__ float sW[64 * 64];
  __shared__ float sf[64 * 64];
  for (int i = threadIdx.x; i < 4096; i += 256) { sW[i] = W[i]; sf[i] = fw[i]; }
  __syncthreads();
  for (int o = threadIdx.x; o < 4096; o += 256) {
    int i = o >> 6, j = o & 63;
    float acc = 0.f;
    #pragma unroll
    for (int k = 0; k < 64; ++k) acc += sW[i * 64 + k] * sf[k * 64 + j];
    Wc[o] = acc;
  }
  if (threadIdx.x < 64) {
    int j = threadIdx.x;
    float acc = fb[j];
    #pragma unroll
    for (int k = 0; k < 64; ++k) acc += b[k] * sf[k * 64 + j];
    bc[j] = acc;
  }
}

__global__ void zero_stats(float* __restrict__ stats) {
  if (threadIdx.x < 256) stats[threadIdx.x] = 0.0f;
}

// ---------------------------------------------------------------------------
// Pass 1: block-local counting sort of an 8192-edge chunk by 128-node bucket.
// Output: stage[blk*8192 ...] coalesced (packed = dstLow<<17|src) + a 783-entry
// ushort offset-table row. No global atomics, no random global writes.
// ---------------------------------------------------------------------------
__global__ __launch_bounds__(512) void pass1_sort(
    const int* __restrict__ src, const int* __restrict__ dst,
    unsigned int* __restrict__ stage, unsigned short* __restrict__ tbl) {
  __shared__ unsigned int hist[NBUCK];
  __shared__ unsigned int ts[512];
  __shared__ unsigned int sorted[P1_CHUNK];
  const int tid = threadIdx.x;
  const int e0 = blockIdx.x * P1_CHUNK;

  for (int b = tid; b < NBUCK; b += 512) hist[b] = 0;
  __syncthreads();

  int dreg[16];                               // dst cached -> no second dst read
  #pragma unroll
  for (int k = 0; k < 16; ++k) {
    int e = e0 + k * 512 + tid;
    int d = (e < N_EDGES) ? dst[e] : -1;
    dreg[k] = d;
    if (d >= 0) atomicAdd(&hist[((unsigned)d) >> BSHIFT], 1u);
  }
  __syncthreads();

  // exclusive scan of hist (thread owns buckets 2t, 2t+1)
  unsigned int v0 = (2 * tid < NBUCK) ? hist[2 * tid] : 0u;
  unsigned int v1 = (2 * tid + 1 < NBUCK) ? hist[2 * tid + 1] : 0u;
  unsigned int run = v0 + v1;
  ts[tid] = run;
  __syncthreads();
  for (int o = 1; o < 512; o <<= 1) {
    unsigned int add = (tid >= o) ? ts[tid - o] : 0u;
    __syncthreads();
    ts[tid] += add;
    __syncthreads();
  }
  const unsigned int excl = ts[tid] - run;
  const unsigned int m = ts[511];             // real edges in this chunk
  unsigned short* trow = tbl + (size_t)blockIdx.x * TBL_STRIDE;
  if (2 * tid < NBUCK)     { hist[2 * tid]     = excl;      trow[2 * tid]     = (unsigned short)excl; }
  if (2 * tid + 1 < NBUCK) { hist[2 * tid + 1] = excl + v0; trow[2 * tid + 1] = (unsigned short)(excl + v0); }
  if (tid == 0) trow[NBUCK] = (unsigned short)m;
  __syncthreads();

  #pragma unroll
  for (int k = 0; k < 16; ++k) {
    int e = e0 + k * 512 + tid;
    int t = dreg[k];
    if (t >= 0) {
      unsigned int pos = atomicAdd(&hist[((unsigned)t) >> BSHIFT], 1u);
      sorted[pos] = (((unsigned)(t & (BNODES - 1))) << 17) | (unsigned)src[e];
    }
  }
  __syncthreads();

  unsigned int* so = stage + (size_t)blockIdx.x * P1_CHUNK;
  for (int i = tid; i < (int)m; i += 512) so[i] = sorted[i];
}

// ---------------------------------------------------------------------------
// Pass 2 (v2): lane-per-segment gather (one thread owns one chunk-segment),
// single read of stage, LDS counting sort to node order. Emits eSrc
// (bucket-padded regions), off/edeg per node, dinv.
// ---------------------------------------------------------------------------
__global__ __launch_bounds__(512) void pass2_sort(
    const unsigned int* __restrict__ stage, const unsigned short* __restrict__ tbl,
    int* __restrict__ eSrc, int* __restrict__ off, int* __restrict__ edeg,
    float* __restrict__ dinv) {
  __shared__ int segbase[NB_P1];              // global index of my segment start
  __shared__ int spre[512];                   // scan ws -> inclusive prefix of seglen
  __shared__ int cnt[BNODES];
  __shared__ int ts[BNODES];
  __shared__ unsigned int raw[BCAP];
  __shared__ int sorted[BCAP];
  const int b = blockIdx.x, tid = threadIdx.x;
  const int n0 = b * BNODES;

  // phase 0: per-segment base & length; scan lengths
  int len = 0;
  if (tid < NB_P1) {
    const unsigned short* trow = tbl + (size_t)tid * TBL_STRIDE;
    int o0 = trow[b], o1 = trow[b + 1];
    segbase[tid] = tid * P1_CHUNK + o0;
    len = o1 - o0;
  }
  if (tid < BNODES) cnt[tid] = 0;
  spre[tid] = len;
  __syncthreads();
  for (int o = 1; o < 512; o <<= 1) {
    int add = (tid >= o) ? spre[tid - o] : 0;
    __syncthreads();
    spre[tid] += add;
    __syncthreads();
  }
  const int m = spre[511];
  const int pref = spre[tid] - len;           // exclusive prefix (my raw[] base)

  // phase A: each lane walks its own segment; gather + histogram + stash
  if (tid < NB_P1) {
    const int base = segbase[tid];
    for (int j = 0; j < len; ++j) {
      unsigned int p = stage[base + j];
      raw[pref + j] = p;
      atomicAdd(&cnt[p >> 17], 1);
    }
  }
  __syncthreads();

  // phase B: node scan -> off/edeg/dinv, cursors
  int v = 0;
  if (tid < BNODES) { v = cnt[tid]; ts[tid] = v; }
  __syncthreads();
  for (int o = 1; o < BNODES; o <<= 1) {
    int add = (tid >= o && tid < BNODES) ? ts[tid - o] : 0;
    __syncthreads();
    if (tid < BNODES) ts[tid] += add;
    __syncthreads();
  }
  if (tid < BNODES) {
    int excl = ts[tid] - v;
    int node = n0 + tid;
    if (node < N_NODES) {
      off[node]  = b * BCAP + excl;
      edeg[node] = v;
      dinv[node] = rsqrtf((float)v + 1.0f);
    }
    cnt[tid] = excl;                          // becomes cursor
  }
  __syncthreads();

  // phase C: LDS scatter into node order
  for (int i = tid; i < m; i += 512) {
    unsigned int p = raw[i];
    int pos = atomicAdd(&cnt[p >> 17], 1);
    if (pos < BCAP) sorted[pos] = (int)(p & SRC_MASK);
  }
  __syncthreads();

  // phase D: coalesced write-out
  int* out = eSrc + (size_t)b * BCAP;
  for (int i = tid; i < m; i += 512) out[i] = sorted[i];
}

// Xs[i][:] = bf16( dinv[i] * x[i][:] )
__global__ void prescale_x(const float* __restrict__ x, const float* __restrict__ dinv,
                           unsigned short* __restrict__ Xs) {
  int idx = blockIdx.x * blockDim.x + threadIdx.x;
  if (idx < N_NODES * D) Xs[idx] = f2bf(dinv[idx >> 6] * x[idx]);
}

// Ys[i][:] = bf16( dinv[i] * relu(Y[i][:]*a + c) )
__global__ void prescale_y(const float* __restrict__ Y, const float* __restrict__ dinv,
                           const float* __restrict__ a, const float* __restrict__ c,
                           unsigned short* __restrict__ Ys) {
  int idx = blockIdx.x * blockDim.x + threadIdx.x;
  if (idx < N_NODES * D) {
    int i = idx >> 6, j = idx & 63;
    Ys[idx] = f2bf(dinv[i] * fmaxf(fmaf(Y[idx], a[j], c[j]), 0.f));
  }
}

// ---------------------------------------------------------------------------
// CSR aggregation: one wave per node, 8 edges per uint4 gather, bf16 output.
// Every edge is covered by a 4-deep independent gather batch (clamped+masked).
//   agg[t] = dinv[t] * ( Xs[t] + sum_{s in N(t)} Xs[s] )
// ---------------------------------------------------------------------------
__global__ __launch_bounds__(256) void agg_csr(
    const int* __restrict__ off, const int* __restrict__ edeg,
    const int* __restrict__ eSrc, const unsigned short* __restrict__ Xs,
    const float* __restrict__ dinv, unsigned short* __restrict__ agg) {
  const int wid = (blockIdx.x * 256 + threadIdx.x) >> 6;
  const int lane = threadIdx.x & 63;
  const int grp = lane >> 3, sub = lane & 7;
  if (wid >= N_NODES) return;
  const int s0 = off[wid];
  const int s1 = s0 + edeg[wid];
  const uint4* XsV = (const uint4*)Xs;        // row r, chunk c at r*8 + c

  float acc[8];
  {
    uint4 u = XsV[(size_t)wid * 8 + sub];     // self loop: only grp 0 adds it
    if (grp != 0) { u.x = 0; u.y = 0; u.z = 0; u.w = 0; }
    acc[0] = __uint_as_float(u.x << 16);
    acc[1] = __uint_as_float(u.x & 0xFFFF0000u);
    acc[2] = __uint_as_float(u.y << 16);
    acc[3] = __uint_as_float(u.y & 0xFFFF0000u);
    acc[4] = __uint_as_float(u.z << 16);
    acc[5] = __uint_as_float(u.z & 0xFFFF0000u);
    acc[6] = __uint_as_float(u.w << 16);
    acc[7] = __uint_as_float(u.w & 0xFFFF0000u);
  }

  const int lim = s1 - 1;                     // valid iff s1 > s0 (loop guard)
  for (int e = s0; e < s1; e += 32) {         // 4 gathers in flight, all edges
    int ea = e + grp, eb = e + 8 + grp, ec = e + 16 + grp, ed = e + 24 + grp;
    int sa = eSrc[min(ea, lim)];
    int sb = eSrc[min(eb, lim)];
    int sc = eSrc[min(ec, lim)];
    int sd = eSrc[min(ed, lim)];
    uint4 ua = XsV[(size_t)sa * 8 + sub];
    uint4 ub = XsV[(size_t)sb * 8 + sub];
    uint4 uc = XsV[(size_t)sc * 8 + sub];
    uint4 ud = XsV[(size_t)sd * 8 + sub];
    if (ea > lim) { ua.x = 0; ua.y = 0; ua.z = 0; ua.w = 0; }
    if (eb > lim) { ub.x = 0; ub.y = 0; ub.z = 0; ub.w = 0; }
    if (ec > lim) { uc.x = 0; uc.y = 0; uc.z = 0; uc.w = 0; }
    if (ed > lim) { ud.x = 0; ud.y = 0; ud.z = 0; ud.w = 0; }
    addu4(acc, ua); addu4(acc, ub); addu4(acc, uc); addu4(acc, ud);
  }

  #pragma unroll
  for (int mk = 8; mk <= 32; mk <<= 1) {
    #pragma unroll
    for (int i = 0; i < 8; ++i) acc[i] += __shfl_xor(acc[i], mk, 64);
  }

  if (grp == 0) {
    float dt = dinv[wid];
    uint4 o;
    o.x = ((unsigned)f2bf(acc[1] * dt) << 16) | f2bf(acc[0] * dt);
    o.y = ((unsigned)f2bf(acc[3] * dt) << 16) | f2bf(acc[2] * dt);
    o.z = ((unsigned)f2bf(acc[5] * dt) << 16) | f2bf(acc[4] * dt);
    o.w = ((unsigned)f2bf(acc[7] * dt) << 16) | f2bf(acc[6] * dt);
    *(uint4*)(agg + (size_t)wid * 64 + sub * 8) = o;
  }
}

// ---------------------------------------------------------------------------
// Y[64-row tile] = A(bf16) @ Wc + bc, fused per-column sum/sumsq partials
// ---------------------------------------------------------------------------
__global__ __launch_bounds__(256) void gemm_stats(
    const unsigned short* __restrict__ A, const float* __restrict__ Wc,
    const float* __restrict__ bc, float* __restrict__ Y,
    float* __restrict__ colsum, float* __restrict__ colsq) {
  __shared__ float sA[64 * 64];
  __shared__ float sW[64 * 64];
  __shared__ float sB[64];
  __shared__ float red[8][64];

  const int tid = threadIdx.x;
  const int c = tid & 63;
  const int rg = tid >> 6;
  const int rowBase = blockIdx.x * 64;

  const unsigned int* A32 = (const unsigned int*)A;   // 2 bf16 per uint, 32/row
  for (int i = tid; i < 2048; i += 256) {
    int rr = i >> 5, cc = i & 31;
    int r = rowBase + rr;
    unsigned int u = (r < N_NODES) ? A32[(size_t)r * 32 + cc] : 0u;
    sA[rr * 64 + cc * 2]     = __uint_as_float(u << 16);
    sA[rr * 64 + cc * 2 + 1] = __uint_as_float(u & 0xFFFF0000u);
  }
  for (int i = tid; i < 4096; i += 256) sW[i] = Wc[i];
  if (tid < 64) sB[tid] = bc[tid];
  __syncthreads();

  float acc[16];
  #pragma unroll
  for (int rr = 0; rr < 16; ++rr) acc[rr] = 0.f;
  const int rA = rg * 16;
  for (int k = 0; k < 64; ++k) {
    float w = sW[k * 64 + c];
    #pragma unroll
    for (int rr = 0; rr < 16; ++rr)
      acc[rr] += sA[(rA + rr) * 64 + k] * w;
  }

  float psum = 0.f, psq = 0.f;
  #pragma unroll
  for (int rr = 0; rr < 16; ++rr) {
    int r = rowBase + rA + rr;
    if (r < N_NODES) {
      float y = acc[rr] + sB[c];
      Y[r * 64 + c] = y;
      psum += y;
      psq += y * y;
    }
  }
  red[rg][c] = psum;
  red[rg + 4][c] = psq;
  __syncthreads();
  if (tid < 64) {
    float s = red[0][c] + red[1][c] + red[2][c] + red[3][c];
    float q = red[4][c] + red[5][c] + red[6][c] + red[7][c];
    atomicAdd(&colsum[c], s);
    atomicAdd(&colsq[c], q);
  }
}

__global__ void finalize_stats(const float* __restrict__ colsum, const float* __restrict__ colsq,
                               const float* __restrict__ g, const float* __restrict__ bt,
                               float* __restrict__ a, float* __restrict__ c) {
  int j = threadIdx.x;
  if (j < 64) {
    float mu = colsum[j] * (1.0f / N_NODES);
    float var = colsq[j] * (1.0f / N_NODES) - mu * mu;
    float s = rsqrtf(var + EPS) * g[j];
    a[j] = s;
    c[j] = bt[j] - mu * s;
  }
}

__global__ void final_norm(float* __restrict__ Y, const float* __restrict__ a,
                           const float* __restrict__ c) {
  int idx = blockIdx.x * blockDim.x + threadIdx.x;
  if (idx < N_NODES * D) {
    int j = idx & 63;
    Y[idx] = fmaxf(fmaf(Y[idx], a[j], c[j]), 0.f);
  }
}

extern "C" void kernel_launch(void* const* d_in, const int* in_sizes, int n_in,
                              void* d_out, int out_size, void* d_ws, size_t ws_size,
                              hipStream_t stream) {
  const float* x   = (const float*)d_in[0];
  const int*   src = (const int*)d_in[1];          // edge_index row 0
  const int*   dst = src + N_EDGES;                // edge_index row 1
  const float* W1  = (const float*)d_in[2];
  const float* b1  = (const float*)d_in[3];
  const float* fw1 = (const float*)d_in[4];
  const float* fb1 = (const float*)d_in[5];
  const float* g1  = (const float*)d_in[6];
  const float* bt1 = (const float*)d_in[7];
  const float* W2  = (const float*)d_in[8];
  const float* b2  = (const float*)d_in[9];
  const float* fw2 = (const float*)d_in[10];
  const float* fb2 = (const float*)d_in[11];
  const float* g2  = (const float*)d_in[12];
  const float* bt2 = (const float*)d_in[13];

  float* Y = (float*)d_out;                        // N x 64, reused y1 -> y2 -> out

  // workspace layout (~41.5 MB).  stage (pass1/2 only) and agg (bf16, per
  // layer) alias the same region: stage dead before first agg_csr write.
  unsigned char* w = (unsigned char*)d_ws;
  unsigned int*   stage = (unsigned int*)w;              // NB_P1*8192 uints = 12,812,288 B
  unsigned short* aggb  = (unsigned short*)w;            // N*64 bf16 = 12,800,000 B (alias)
  size_t ofs = ((size_t)NB_P1 * P1_CHUNK * 4 + 255) & ~(size_t)255;
  float*          dinv  = (float*)(w + ofs);             // N floats
  unsigned short* Xs    = (unsigned short*)(dinv + N_NODES);          // N*64 bf16
  int*            eSrc  = (int*)(Xs + (size_t)N_NODES * D);           // NBUCK*BCAP ints
  int*            off   = eSrc + (size_t)NBUCK * BCAP;   // N ints
  int*            edeg  = off + N_NODES;                 // N ints
  unsigned short* tbl   = (unsigned short*)(edeg + N_NODES);          // NB_P1*784 ushort
  float* Wc1  = (float*)(tbl + (size_t)NB_P1 * TBL_STRIDE);           // 4096
  float* bc1  = Wc1 + 4096;                        // 64
  float* Wc2  = bc1 + 64;                          // 4096
  float* bc2  = Wc2 + 4096;                        // 64
  float* sum1 = bc2 + 64;                          // 64  (sum1..sq2 contiguous 256)
  float* sq1  = sum1 + 64;
  float* sum2 = sq1 + 64;
  float* sq2  = sum2 + 64;
  float* a1   = sq2 + 64;
  float* c1   = a1 + 64;
  float* a2   = c1 + 64;
  float* c2   = a2 + 64;

  const int nd = N_NODES * D;
  dim3 blk(256);

  combine_weights<<<2, blk, 0, stream>>>(W1, b1, fw1, fb1, W2, b2, fw2, fb2,
                                         Wc1, bc1, Wc2, bc2);
  zero_stats<<<1, blk, 0, stream>>>(sum1);

  // ---- two-pass partition: block-local sort -> per-bucket node CSR ----
  pass1_sort<<<NB_P1, 512, 0, stream>>>(src, dst, stage, tbl);
  pass2_sort<<<NBUCK, 512, 0, stream>>>(stage, tbl, eSrc, off, edeg, dinv);

  // ---- layer 1 ----
  prescale_x<<<(nd + 255) / 256, blk, 0, stream>>>(x, dinv, Xs);
  agg_csr<<<(nd + 255) / 256, blk, 0, stream>>>(off, edeg, eSrc, Xs, dinv, aggb);
  gemm_stats<<<(N_NODES + 63) / 64, blk, 0, stream>>>(aggb, Wc1, bc1, Y, sum1, sq1);
  finalize_stats<<<1, 64, 0, stream>>>(sum1, sq1, g1, bt1, a1, c1);

  // ---- layer 2 (BN-affine+ReLU of layer 1 fused into the prescale) ----
  prescale_y<<<(nd + 255) / 256, blk, 0, stream>>>(Y, dinv, a1, c1, Xs);
  agg_csr<<<(nd + 255) / 256, blk, 0, stream>>>(off, edeg, eSrc, Xs, dinv, aggb);
  gemm_stats<<<(N_NODES + 63) / 64, blk, 0, stream>>>(aggb, Wc2, bc2, Y, sum2, sq2);
  finalize_stats<<<1, 64, 0, stream>>>(sum2, sq2, g2, bt2, a2, c2);

  final_norm<<<(nd + 255) / 256, blk, 0, stream>>>(Y, a2, c2);
}

// Round 9
// 364.105 us; speedup vs baseline: 8.9834x; 1.2022x over previous
//
#include <hip/hip_runtime.h>

#define N_NODES 100000
#define N_EDGES 3200000
#define D 64
#define EPS 1e-5f

#define BSHIFT 7
#define BNODES 128                                          // nodes per bucket
#define NBUCK ((N_NODES + BNODES - 1) / BNODES)             // 782
#define P1_CHUNK 8192
#define NB_P1 ((N_EDGES + P1_CHUNK - 1) / P1_CHUNK)         // 391
#define SRC_MASK 0x1FFFFu                                   // 17 bits >= 100000
#define BCAP 4480                                           // bucket region cap
#define TBL_STRIDE 784                                      // 783 entries + pad

typedef __attribute__((ext_vector_type(8))) short bf16x8;   // 8 bf16 = 4 VGPRs
typedef __attribute__((ext_vector_type(4))) float f32x4;

__device__ __forceinline__ unsigned short f2bf(float f) {
  unsigned int u = __float_as_uint(f);
  u += 0x7FFFu + ((u >> 16) & 1u);          // round to nearest even
  return (unsigned short)(u >> 16);
}
// add 8 bf16 (packed in uint4) into 8 fp32 accumulators
__device__ __forceinline__ void addu4(float acc[8], uint4 u) {
  acc[0] += __uint_as_float(u.x << 16);
  acc[1] += __uint_as_float(u.x & 0xFFFF0000u);
  acc[2] += __uint_as_float(u.y << 16);
  acc[3] += __uint_as_float(u.y & 0xFFFF0000u);
  acc[4] += __uint_as_float(u.z << 16);
  acc[5] += __uint_as_float(u.z & 0xFFFF0000u);
  acc[6] += __uint_as_float(u.w << 16);
  acc[7] += __uint_as_float(u.w & 0xFFFF0000u);
}

// ---------------------------------------------------------------------------
// Fold GCNConv + FC into one 64x64 (Wc = W@fw) and emit it pre-swizzled into
// MFMA B-fragment order, bf16:  frag f=(nt*2+kh), lane L, elem j  holds
// B[k = (L>>4)*8 + j + kh*32][n = nt*16 + (L&15)].  bc = b@fw + fb (fp32).
// ---------------------------------------------------------------------------
__global__ __launch_bounds__(256) void combine_weights(
    const float* __restrict__ W1, const float* __restrict__ b1,
    const float* __restrict__ fw1, const float* __restrict__ fb1,
    const float* __restrict__ W2, const float* __restrict__ b2,
    const float* __restrict__ fw2, const float* __restrict__ fb2,
    unsigned int* __restrict__ WcB1, float* __restrict__ bc1,
    unsigned int* __restrict__ WcB2, float* __restrict__ bc2) {
  const float* W  = blockIdx.x ? W2  : W1;
  const float* fw = blockIdx.x ? fw2 : fw1;
  const float* b  = blockIdx.x ? b2  : b1;
  const float* fb = blockIdx.x ? fb2 : fb1;
  unsigned int* WcB = blockIdx.x ? WcB2 : WcB1;
  float* bc = blockIdx.x ? bc2 : bc1;

  __shared__ float sW[64 * 64];
  __shared__ float sf[64 * 64];
  __shared__ float sC[64 * 64];
  for (int i = threadIdx.x; i < 4096; i += 256) { sW[i] = W[i]; sf[i] = fw[i]; }
  __syncthreads();
  for (int o = threadIdx.x; o < 4096; o += 256) {
    int i = o >> 6, j = o & 63;
    float acc = 0.f;
    #pragma unroll
    for (int k = 0; k < 64; ++k) acc += sW[i * 64 + k] * sf[k * 64 + j];
    sC[o] = acc;
  }
  __syncthreads();
  // emit B-fragment-swizzled bf16 (2048 uints; uint jj packs elems 2jj,2jj+1)
  for (int o = threadIdx.x; o < 2048; o += 256) {
    int jj = o & 3, L = (o >> 2) & 63, kh = (o >> 8) & 1, nt = o >> 9;
    int k0 = (L >> 4) * 8 + jj * 2 + kh * 32;
    int n  = nt * 16 + (L & 15);
    unsigned int lo = f2bf(sC[k0 * 64 + n]);
    unsigned int hi = f2bf(sC[(k0 + 1) * 64 + n]);
    WcB[o] = (hi << 16) | lo;
  }
  if (threadIdx.x < 64) {
    int j = threadIdx.x;
    float acc = fb[j];
    #pragma unroll
    for (int k = 0; k < 64; ++k) acc += b[k] * sf[k * 64 + j];
    bc[j] = acc;
  }
}

__global__ void zero_stats(float* __restrict__ stats) {
  if (threadIdx.x < 256) stats[threadIdx.x] = 0.0f;
}

// ---------------------------------------------------------------------------
// Pass 1: block-local counting sort of an 8192-edge chunk by 128-node bucket.
// ---------------------------------------------------------------------------
__global__ __launch_bounds__(512) void pass1_sort(
    const int* __restrict__ src, const int* __restrict__ dst,
    unsigned int* __restrict__ stage, unsigned short* __restrict__ tbl) {
  __shared__ unsigned int hist[NBUCK];
  __shared__ unsigned int ts[512];
  __shared__ unsigned int sorted[P1_CHUNK];
  const int tid = threadIdx.x;
  const int e0 = blockIdx.x * P1_CHUNK;

  for (int b = tid; b < NBUCK; b += 512) hist[b] = 0;
  __syncthreads();

  int dreg[16];
  #pragma unroll
  for (int k = 0; k < 16; ++k) {
    int e = e0 + k * 512 + tid;
    int d = (e < N_EDGES) ? dst[e] : -1;
    dreg[k] = d;
    if (d >= 0) atomicAdd(&hist[((unsigned)d) >> BSHIFT], 1u);
  }
  __syncthreads();

  unsigned int v0 = (2 * tid < NBUCK) ? hist[2 * tid] : 0u;
  unsigned int v1 = (2 * tid + 1 < NBUCK) ? hist[2 * tid + 1] : 0u;
  unsigned int run = v0 + v1;
  ts[tid] = run;
  __syncthreads();
  for (int o = 1; o < 512; o <<= 1) {
    unsigned int add = (tid >= o) ? ts[tid - o] : 0u;
    __syncthreads();
    ts[tid] += add;
    __syncthreads();
  }
  const unsigned int excl = ts[tid] - run;
  const unsigned int m = ts[511];
  unsigned short* trow = tbl + (size_t)blockIdx.x * TBL_STRIDE;
  if (2 * tid < NBUCK)     { hist[2 * tid]     = excl;      trow[2 * tid]     = (unsigned short)excl; }
  if (2 * tid + 1 < NBUCK) { hist[2 * tid + 1] = excl + v0; trow[2 * tid + 1] = (unsigned short)(excl + v0); }
  if (tid == 0) trow[NBUCK] = (unsigned short)m;
  __syncthreads();

  #pragma unroll
  for (int k = 0; k < 16; ++k) {
    int e = e0 + k * 512 + tid;
    int t = dreg[k];
    if (t >= 0) {
      unsigned int pos = atomicAdd(&hist[((unsigned)t) >> BSHIFT], 1u);
      sorted[pos] = (((unsigned)(t & (BNODES - 1))) << 17) | (unsigned)src[e];
    }
  }
  __syncthreads();

  unsigned int* so = stage + (size_t)blockIdx.x * P1_CHUNK;
  for (int i = tid; i < (int)m; i += 512) so[i] = sorted[i];
}

// ---------------------------------------------------------------------------
// Pass 2: lane-per-segment gather, single read of stage, LDS counting sort.
// ---------------------------------------------------------------------------
__global__ __launch_bounds__(512) void pass2_sort(
    const unsigned int* __restrict__ stage, const unsigned short* __restrict__ tbl,
    int* __restrict__ eSrc, int* __restrict__ off, int* __restrict__ edeg,
    float* __restrict__ dinv) {
  __shared__ int segbase[NB_P1];
  __shared__ int spre[512];
  __shared__ int cnt[BNODES];
  __shared__ int ts[BNODES];
  __shared__ unsigned int raw[BCAP];
  __shared__ int sorted[BCAP];
  const int b = blockIdx.x, tid = threadIdx.x;
  const int n0 = b * BNODES;

  int len = 0;
  if (tid < NB_P1) {
    const unsigned short* trow = tbl + (size_t)tid * TBL_STRIDE;
    int o0 = trow[b], o1 = trow[b + 1];
    segbase[tid] = tid * P1_CHUNK + o0;
    len = o1 - o0;
  }
  if (tid < BNODES) cnt[tid] = 0;
  spre[tid] = len;
  __syncthreads();
  for (int o = 1; o < 512; o <<= 1) {
    int add = (tid >= o) ? spre[tid - o] : 0;
    __syncthreads();
    spre[tid] += add;
    __syncthreads();
  }
  const int m = spre[511];
  const int pref = spre[tid] - len;

  if (tid < NB_P1) {
    const int base = segbase[tid];
    for (int j = 0; j < len; ++j) {
      unsigned int p = stage[base + j];
      raw[pref + j] = p;
      atomicAdd(&cnt[p >> 17], 1);
    }
  }
  __syncthreads();

  int v = 0;
  if (tid < BNODES) { v = cnt[tid]; ts[tid] = v; }
  __syncthreads();
  for (int o = 1; o < BNODES; o <<= 1) {
    int add = (tid >= o && tid < BNODES) ? ts[tid - o] : 0;
    __syncthreads();
    if (tid < BNODES) ts[tid] += add;
    __syncthreads();
  }
  if (tid < BNODES) {
    int excl = ts[tid] - v;
    int node = n0 + tid;
    if (node < N_NODES) {
      off[node]  = b * BCAP + excl;
      edeg[node] = v;
      dinv[node] = rsqrtf((float)v + 1.0f);
    }
    cnt[tid] = excl;
  }
  __syncthreads();

  for (int i = tid; i < m; i += 512) {
    unsigned int p = raw[i];
    int pos = atomicAdd(&cnt[p >> 17], 1);
    if (pos < BCAP) sorted[pos] = (int)(p & SRC_MASK);
  }
  __syncthreads();

  int* out = eSrc + (size_t)b * BCAP;
  for (int i = tid; i < m; i += 512) out[i] = sorted[i];
}

// Xs[i][:] = bf16( dinv[i] * x[i][:] )
__global__ void prescale_x(const float* __restrict__ x, const float* __restrict__ dinv,
                           unsigned short* __restrict__ Xs) {
  int idx = blockIdx.x * blockDim.x + threadIdx.x;
  if (idx < N_NODES * D) Xs[idx] = f2bf(dinv[idx >> 6] * x[idx]);
}

// Ys[i][:] = bf16( dinv[i] * relu(Y[i][:]*a + c) )
__global__ void prescale_y(const float* __restrict__ Y, const float* __restrict__ dinv,
                           const float* __restrict__ a, const float* __restrict__ c,
                           unsigned short* __restrict__ Ys) {
  int idx = blockIdx.x * blockDim.x + threadIdx.x;
  if (idx < N_NODES * D) {
    int i = idx >> 6, j = idx & 63;
    Ys[idx] = f2bf(dinv[i] * fmaxf(fmaf(Y[idx], a[j], c[j]), 0.f));
  }
}

// ---------------------------------------------------------------------------
// CSR aggregation: one wave per node, 8 edges per uint4 gather, bf16 output.
// ---------------------------------------------------------------------------
__global__ __launch_bounds__(256) void agg_csr(
    const int* __restrict__ off, const int* __restrict__ edeg,
    const int* __restrict__ eSrc, const unsigned short* __restrict__ Xs,
    const float* __restrict__ dinv, unsigned short* __restrict__ agg) {
  const int wid = (blockIdx.x * 256 + threadIdx.x) >> 6;
  const int lane = threadIdx.x & 63;
  const int grp = lane >> 3, sub = lane & 7;
  if (wid >= N_NODES) return;
  const int s0 = off[wid];
  const int s1 = s0 + edeg[wid];
  const uint4* XsV = (const uint4*)Xs;

  float acc[8];
  {
    uint4 u = XsV[(size_t)wid * 8 + sub];     // self loop: only grp 0 adds it
    if (grp != 0) { u.x = 0; u.y = 0; u.z = 0; u.w = 0; }
    acc[0] = __uint_as_float(u.x << 16);
    acc[1] = __uint_as_float(u.x & 0xFFFF0000u);
    acc[2] = __uint_as_float(u.y << 16);
    acc[3] = __uint_as_float(u.y & 0xFFFF0000u);
    acc[4] = __uint_as_float(u.z << 16);
    acc[5] = __uint_as_float(u.z & 0xFFFF0000u);
    acc[6] = __uint_as_float(u.w << 16);
    acc[7] = __uint_as_float(u.w & 0xFFFF0000u);
  }

  const int lim = s1 - 1;
  for (int e = s0; e < s1; e += 32) {         // 4 gathers in flight, all edges
    int ea = e + grp, eb = e + 8 + grp, ec = e + 16 + grp, ed = e + 24 + grp;
    int sa = eSrc[min(ea, lim)];
    int sb = eSrc[min(eb, lim)];
    int sc = eSrc[min(ec, lim)];
    int sd = eSrc[min(ed, lim)];
    uint4 ua = XsV[(size_t)sa * 8 + sub];
    uint4 ub = XsV[(size_t)sb * 8 + sub];
    uint4 uc = XsV[(size_t)sc * 8 + sub];
    uint4 ud = XsV[(size_t)sd * 8 + sub];
    if (ea > lim) { ua.x = 0; ua.y = 0; ua.z = 0; ua.w = 0; }
    if (eb > lim) { ub.x = 0; ub.y = 0; ub.z = 0; ub.w = 0; }
    if (ec > lim) { uc.x = 0; uc.y = 0; uc.z = 0; uc.w = 0; }
    if (ed > lim) { ud.x = 0; ud.y = 0; ud.z = 0; ud.w = 0; }
    addu4(acc, ua); addu4(acc, ub); addu4(acc, uc); addu4(acc, ud);
  }

  #pragma unroll
  for (int mk = 8; mk <= 32; mk <<= 1) {
    #pragma unroll
    for (int i = 0; i < 8; ++i) acc[i] += __shfl_xor(acc[i], mk, 64);
  }

  if (grp == 0) {
    float dt = dinv[wid];
    uint4 o;
    o.x = ((unsigned)f2bf(acc[1] * dt) << 16) | f2bf(acc[0] * dt);
    o.y = ((unsigned)f2bf(acc[3] * dt) << 16) | f2bf(acc[2] * dt);
    o.z = ((unsigned)f2bf(acc[5] * dt) << 16) | f2bf(acc[4] * dt);
    o.w = ((unsigned)f2bf(acc[7] * dt) << 16) | f2bf(acc[6] * dt);
    *(uint4*)(agg + (size_t)wid * 64 + sub * 8) = o;
  }
}

// ---------------------------------------------------------------------------
// MFMA GEMM: Y[128-row block] = A(bf16) @ WcB + bc, fused col sum/sumsq.
// Wave w, loop l: rows [blk*128 + l*64 + w*16, +16).  Zero LDS for A/B.
//  A-frag: lane holds row (base + (L&15)), k = (L>>4)*8 + j  -> one uint4.
//  C/D:    row = base + (L>>4)*4 + reg, col = nt*16 + (L&15).
// ---------------------------------------------------------------------------
__global__ __launch_bounds__(256) void gemm_stats(
    const unsigned short* __restrict__ A, const unsigned int* __restrict__ WcB,
    const float* __restrict__ bc, float* __restrict__ Y,
    float* __restrict__ colsum, float* __restrict__ colsq) {
  const int tid = threadIdx.x;
  const int L = tid & 63, wv = tid >> 6;
  const int quad = L >> 4, l16 = L & 15;

  const bf16x8* Wv = (const bf16x8*)WcB;      // frag f at Wv[f*64 + L]
  bf16x8 bfr[4][2];
  #pragma unroll
  for (int nt = 0; nt < 4; ++nt)
    #pragma unroll
    for (int kh = 0; kh < 2; ++kh)
      bfr[nt][kh] = Wv[(nt * 2 + kh) * 64 + L];
  float bcv[4];
  #pragma unroll
  for (int nt = 0; nt < 4; ++nt) bcv[nt] = bc[nt * 16 + l16];

  const bf16x8* Av = (const bf16x8*)A;        // 8 chunks per row
  float psum[4] = {0.f, 0.f, 0.f, 0.f}, psq[4] = {0.f, 0.f, 0.f, 0.f};

  #pragma unroll
  for (int loop = 0; loop < 2; ++loop) {
    const int rowbase = blockIdx.x * 128 + loop * 64 + wv * 16;
    const int m = min(rowbase + l16, N_NODES - 1);
    bf16x8 a0 = Av[(size_t)m * 8 + quad];
    bf16x8 a1 = Av[(size_t)m * 8 + 4 + quad];
    #pragma unroll
    for (int nt = 0; nt < 4; ++nt) {
      f32x4 acc = {0.f, 0.f, 0.f, 0.f};
      acc = __builtin_amdgcn_mfma_f32_16x16x32_bf16(a0, bfr[nt][0], acc, 0, 0, 0);
      acc = __builtin_amdgcn_mfma_f32_16x16x32_bf16(a1, bfr[nt][1], acc, 0, 0, 0);
      #pragma unroll
      for (int r = 0; r < 4; ++r) {
        int row = rowbase + quad * 4 + r;
        if (row < N_NODES) {
          float y = acc[r] + bcv[nt];
          Y[(size_t)row * 64 + nt * 16 + l16] = y;
          psum[nt] += y;
          psq[nt] += y * y;
        }
      }
    }
  }

  // reduce stats: over quad groups (lanes same l16), then over waves via LDS
  #pragma unroll
  for (int nt = 0; nt < 4; ++nt) {
    psum[nt] += __shfl_xor(psum[nt], 16, 64);
    psum[nt] += __shfl_xor(psum[nt], 32, 64);
    psq[nt]  += __shfl_xor(psq[nt], 16, 64);
    psq[nt]  += __shfl_xor(psq[nt], 32, 64);
  }
  __shared__ float rsum[4][64];
  __shared__ float rsq[4][64];
  if (L < 16) {
    #pragma unroll
    for (int nt = 0; nt < 4; ++nt) {
      rsum[wv][nt * 16 + L] = psum[nt];
      rsq[wv][nt * 16 + L]  = psq[nt];
    }
  }
  __syncthreads();
  if (tid < 64) {
    float s = rsum[0][tid] + rsum[1][tid] + rsum[2][tid] + rsum[3][tid];
    float q = rsq[0][tid] + rsq[1][tid] + rsq[2][tid] + rsq[3][tid];
    atomicAdd(&colsum[tid], s);
    atomicAdd(&colsq[tid], q);
  }
}

__global__ void finalize_stats(const float* __restrict__ colsum, const float* __restrict__ colsq,
                               const float* __restrict__ g, const float* __restrict__ bt,
                               float* __restrict__ a, float* __restrict__ c) {
  int j = threadIdx.x;
  if (j < 64) {
    float mu = colsum[j] * (1.0f / N_NODES);
    float var = colsq[j] * (1.0f / N_NODES) - mu * mu;
    float s = rsqrtf(var + EPS) * g[j];
    a[j] = s;
    c[j] = bt[j] - mu * s;
  }
}

__global__ void final_norm(float* __restrict__ Y, const float* __restrict__ a,
                           const float* __restrict__ c) {
  int idx = blockIdx.x * blockDim.x + threadIdx.x;
  if (idx < N_NODES * D) {
    int j = idx & 63;
    Y[idx] = fmaxf(fmaf(Y[idx], a[j], c[j]), 0.f);
  }
}

extern "C" void kernel_launch(void* const* d_in, const int* in_sizes, int n_in,
                              void* d_out, int out_size, void* d_ws, size_t ws_size,
                              hipStream_t stream) {
  const float* x   = (const float*)d_in[0];
  const int*   src = (const int*)d_in[1];          // edge_index row 0
  const int*   dst = src + N_EDGES;                // edge_index row 1
  const float* W1  = (const float*)d_in[2];
  const float* b1  = (const float*)d_in[3];
  const float* fw1 = (const float*)d_in[4];
  const float* fb1 = (const float*)d_in[5];
  const float* g1  = (const float*)d_in[6];
  const float* bt1 = (const float*)d_in[7];
  const float* W2  = (const float*)d_in[8];
  const float* b2  = (const float*)d_in[9];
  const float* fw2 = (const float*)d_in[10];
  const float* fb2 = (const float*)d_in[11];
  const float* g2  = (const float*)d_in[12];
  const float* bt2 = (const float*)d_in[13];

  float* Y = (float*)d_out;                        // N x 64, reused y1 -> y2 -> out

  // workspace layout (~41.5 MB). stage (partition only) aliases aggb (bf16).
  unsigned char* w = (unsigned char*)d_ws;
  unsigned int*   stage = (unsigned int*)w;              // NB_P1*8192 uints
  unsigned short* aggb  = (unsigned short*)w;            // N*64 bf16 (alias)
  size_t ofs = ((size_t)NB_P1 * P1_CHUNK * 4 + 255) & ~(size_t)255;
  float*          dinv  = (float*)(w + ofs);             // N floats
  unsigned short* Xs    = (unsigned short*)(dinv + N_NODES);          // N*64 bf16
  int*            eSrc  = (int*)(Xs + (size_t)N_NODES * D);           // NBUCK*BCAP ints
  int*            off   = eSrc + (size_t)NBUCK * BCAP;   // N ints
  int*            edeg  = off + N_NODES;                 // N ints
  unsigned short* tbl   = (unsigned short*)(edeg + N_NODES);          // NB_P1*784 ushort
  unsigned int* WcB1 = (unsigned int*)(tbl + (size_t)NB_P1 * TBL_STRIDE); // 2048
  float* bc1  = (float*)(WcB1 + 2048);             // 64
  unsigned int* WcB2 = (unsigned int*)(bc1 + 64);  // 2048
  float* bc2  = (float*)(WcB2 + 2048);             // 64
  float* sum1 = bc2 + 64;                          // 64  (sum1..sq2 contiguous 256)
  float* sq1  = sum1 + 64;
  float* sum2 = sq1 + 64;
  float* sq2  = sum2 + 64;
  float* a1   = sq2 + 64;
  float* c1   = a1 + 64;
  float* a2   = c1 + 64;
  float* c2   = a2 + 64;

  const int nd = N_NODES * D;
  dim3 blk(256);

  combine_weights<<<2, blk, 0, stream>>>(W1, b1, fw1, fb1, W2, b2, fw2, fb2,
                                         WcB1, bc1, WcB2, bc2);
  zero_stats<<<1, blk, 0, stream>>>(sum1);

  // ---- two-pass partition: block-local sort -> per-bucket node CSR ----
  pass1_sort<<<NB_P1, 512, 0, stream>>>(src, dst, stage, tbl);
  pass2_sort<<<NBUCK, 512, 0, stream>>>(stage, tbl, eSrc, off, edeg, dinv);

  // ---- layer 1 ----
  prescale_x<<<(nd + 255) / 256, blk, 0, stream>>>(x, dinv, Xs);
  agg_csr<<<(nd + 255) / 256, blk, 0, stream>>>(off, edeg, eSrc, Xs, dinv, aggb);
  gemm_stats<<<(N_NODES + 127) / 128, blk, 0, stream>>>(aggb, WcB1, bc1, Y, sum1, sq1);
  finalize_stats<<<1, 64, 0, stream>>>(sum1, sq1, g1, bt1, a1, c1);

  // ---- layer 2 (BN-affine+ReLU of layer 1 fused into the prescale) ----
  prescale_y<<<(nd + 255) / 256, blk, 0, stream>>>(Y, dinv, a1, c1, Xs);
  agg_csr<<<(nd + 255) / 256, blk, 0, stream>>>(off, edeg, eSrc, Xs, dinv, aggb);
  gemm_stats<<<(N_NODES + 127) / 128, blk, 0, stream>>>(aggb, WcB2, bc2, Y, sum2, sq2);
  finalize_stats<<<1, 64, 0, stream>>>(sum2, sq2, g2, bt2, a2, c2);

  final_norm<<<(nd + 255) / 256, blk, 0, stream>>>(Y, a2, c2);
}

// Round 10
// 354.587 us; speedup vs baseline: 9.2245x; 1.0268x over previous
//
#include <hip/hip_runtime.h>

#define N_NODES 100000
#define N_EDGES 3200000
#define D 64
#define EPS 1e-5f

#define BSHIFT 7
#define BNODES 128                                          // nodes per bucket
#define NBUCK ((N_NODES + BNODES - 1) / BNODES)             // 782
#define P1_CHUNK 8192
#define NB_P1 ((N_EDGES + P1_CHUNK - 1) / P1_CHUNK)         // 391
#define SRC_MASK 0x1FFFFu                                   // 17 bits >= 100000
#define BCAP 4480                                           // bucket region cap
#define TBL_STRIDE 784                                      // 783 entries + pad

typedef __attribute__((ext_vector_type(8))) short bf16x8;   // 8 bf16 = 4 VGPRs
typedef __attribute__((ext_vector_type(4))) float f32x4;

__device__ __forceinline__ unsigned short f2bf(float f) {
  unsigned int u = __float_as_uint(f);
  u += 0x7FFFu + ((u >> 16) & 1u);          // round to nearest even
  return (unsigned short)(u >> 16);
}
__device__ __forceinline__ float bf2f(unsigned short h) {
  return __uint_as_float(((unsigned int)h) << 16);
}
__device__ __forceinline__ float2 bfpair(unsigned int u) {
  return make_float2(__uint_as_float(u << 16), __uint_as_float(u & 0xFFFF0000u));
}
// add 8 bf16 (packed in uint4) into 4 float2 accumulators (pairs -> v_pk_add)
__device__ __forceinline__ void addp(float2 a[4], uint4 u) {
  a[0] += bfpair(u.x);
  a[1] += bfpair(u.y);
  a[2] += bfpair(u.z);
  a[3] += bfpair(u.w);
}

// ---------------------------------------------------------------------------
// blocks 0,1: fold GCNConv+FC into 64x64, emit MFMA-B-swizzled bf16 + bc.
// block 2: zero the 256-float BN stat accumulators.
// ---------------------------------------------------------------------------
__global__ __launch_bounds__(256) void combine_weights(
    const float* __restrict__ W1, const float* __restrict__ b1,
    const float* __restrict__ fw1, const float* __restrict__ fb1,
    const float* __restrict__ W2, const float* __restrict__ b2,
    const float* __restrict__ fw2, const float* __restrict__ fb2,
    unsigned int* __restrict__ WcB1, float* __restrict__ bc1,
    unsigned int* __restrict__ WcB2, float* __restrict__ bc2,
    float* __restrict__ stats) {
  if (blockIdx.x == 2) {
    if (threadIdx.x < 256) stats[threadIdx.x] = 0.0f;
    return;
  }
  const float* W  = blockIdx.x ? W2  : W1;
  const float* fw = blockIdx.x ? fw2 : fw1;
  const float* b  = blockIdx.x ? b2  : b1;
  const float* fb = blockIdx.x ? fb2 : fb1;
  unsigned int* WcB = blockIdx.x ? WcB2 : WcB1;
  float* bc = blockIdx.x ? bc2 : bc1;

  __shared__ float sW[64 * 64];
  __shared__ float sf[64 * 64];
  __shared__ float sC[64 * 64];
  for (int i = threadIdx.x; i < 4096; i += 256) { sW[i] = W[i]; sf[i] = fw[i]; }
  __syncthreads();
  for (int o = threadIdx.x; o < 4096; o += 256) {
    int i = o >> 6, j = o & 63;
    float acc = 0.f;
    #pragma unroll
    for (int k = 0; k < 64; ++k) acc += sW[i * 64 + k] * sf[k * 64 + j];
    sC[o] = acc;
  }
  __syncthreads();
  // B-fragment swizzle: frag f=(nt*2+kh), lane L, elem j -> B[(L>>4)*8+j+kh*32][nt*16+(L&15)]
  for (int o = threadIdx.x; o < 2048; o += 256) {
    int jj = o & 3, L = (o >> 2) & 63, kh = (o >> 8) & 1, nt = o >> 9;
    int k0 = (L >> 4) * 8 + jj * 2 + kh * 32;
    int n  = nt * 16 + (L & 15);
    unsigned int lo = f2bf(sC[k0 * 64 + n]);
    unsigned int hi = f2bf(sC[(k0 + 1) * 64 + n]);
    WcB[o] = (hi << 16) | lo;
  }
  if (threadIdx.x < 64) {
    int j = threadIdx.x;
    float acc = fb[j];
    #pragma unroll
    for (int k = 0; k < 64; ++k) acc += b[k] * sf[k * 64 + j];
    bc[j] = acc;
  }
}

// ---------------------------------------------------------------------------
// Pass 1: block-local counting sort of an 8192-edge chunk by 128-node bucket.
// ---------------------------------------------------------------------------
__global__ __launch_bounds__(512) void pass1_sort(
    const int* __restrict__ src, const int* __restrict__ dst,
    unsigned int* __restrict__ stage, unsigned short* __restrict__ tbl) {
  __shared__ unsigned int hist[NBUCK];
  __shared__ unsigned int ts[512];
  __shared__ unsigned int sorted[P1_CHUNK];
  const int tid = threadIdx.x;
  const int e0 = blockIdx.x * P1_CHUNK;

  for (int b = tid; b < NBUCK; b += 512) hist[b] = 0;
  __syncthreads();

  int dreg[16];
  #pragma unroll
  for (int k = 0; k < 16; ++k) {
    int e = e0 + k * 512 + tid;
    int d = (e < N_EDGES) ? dst[e] : -1;
    dreg[k] = d;
    if (d >= 0) atomicAdd(&hist[((unsigned)d) >> BSHIFT], 1u);
  }
  __syncthreads();

  unsigned int v0 = (2 * tid < NBUCK) ? hist[2 * tid] : 0u;
  unsigned int v1 = (2 * tid + 1 < NBUCK) ? hist[2 * tid + 1] : 0u;
  unsigned int run = v0 + v1;
  ts[tid] = run;
  __syncthreads();
  for (int o = 1; o < 512; o <<= 1) {
    unsigned int add = (tid >= o) ? ts[tid - o] : 0u;
    __syncthreads();
    ts[tid] += add;
    __syncthreads();
  }
  const unsigned int excl = ts[tid] - run;
  const unsigned int m = ts[511];
  unsigned short* trow = tbl + (size_t)blockIdx.x * TBL_STRIDE;
  if (2 * tid < NBUCK)     { hist[2 * tid]     = excl;      trow[2 * tid]     = (unsigned short)excl; }
  if (2 * tid + 1 < NBUCK) { hist[2 * tid + 1] = excl + v0; trow[2 * tid + 1] = (unsigned short)(excl + v0); }
  if (tid == 0) trow[NBUCK] = (unsigned short)m;
  __syncthreads();

  #pragma unroll
  for (int k = 0; k < 16; ++k) {
    int e = e0 + k * 512 + tid;
    int t = dreg[k];
    if (t >= 0) {
      unsigned int pos = atomicAdd(&hist[((unsigned)t) >> BSHIFT], 1u);
      sorted[pos] = (((unsigned)(t & (BNODES - 1))) << 17) | (unsigned)src[e];
    }
  }
  __syncthreads();

  unsigned int* so = stage + (size_t)blockIdx.x * P1_CHUNK;
  for (int i = tid; i < (int)m; i += 512) so[i] = sorted[i];
}

// ---------------------------------------------------------------------------
// Pass 2: lane-per-segment gather -> LDS counting sort to node CSR, plus
// fused layer-1 prescale:  Xs[i][:] = bf16(dinv[i] * x[i][:])
// ---------------------------------------------------------------------------
__global__ __launch_bounds__(512) void pass2_sort(
    const unsigned int* __restrict__ stage, const unsigned short* __restrict__ tbl,
    int* __restrict__ eSrc, int* __restrict__ off, int* __restrict__ edeg,
    float* __restrict__ dinv, const float* __restrict__ x,
    unsigned short* __restrict__ Xs) {
  __shared__ int segbase[NB_P1];
  __shared__ int spre[512];
  __shared__ int cnt[BNODES];
  __shared__ int ts[BNODES];
  __shared__ float dinvL[BNODES];
  __shared__ unsigned int raw[BCAP];
  __shared__ int sorted[BCAP];
  const int b = blockIdx.x, tid = threadIdx.x;
  const int n0 = b * BNODES;

  int len = 0;
  if (tid < NB_P1) {
    const unsigned short* trow = tbl + (size_t)tid * TBL_STRIDE;
    int o0 = trow[b], o1 = trow[b + 1];
    segbase[tid] = tid * P1_CHUNK + o0;
    len = o1 - o0;
  }
  if (tid < BNODES) cnt[tid] = 0;
  spre[tid] = len;
  __syncthreads();
  for (int o = 1; o < 512; o <<= 1) {
    int add = (tid >= o) ? spre[tid - o] : 0;
    __syncthreads();
    spre[tid] += add;
    __syncthreads();
  }
  const int m = spre[511];
  const int pref = spre[tid] - len;

  if (tid < NB_P1) {
    const int base = segbase[tid];
    for (int j = 0; j < len; ++j) {
      unsigned int p = stage[base + j];
      raw[pref + j] = p;
      atomicAdd(&cnt[p >> 17], 1);
    }
  }
  __syncthreads();

  int v = 0;
  if (tid < BNODES) { v = cnt[tid]; ts[tid] = v; }
  __syncthreads();
  for (int o = 1; o < BNODES; o <<= 1) {
    int add = (tid >= o && tid < BNODES) ? ts[tid - o] : 0;
    __syncthreads();
    if (tid < BNODES) ts[tid] += add;
    __syncthreads();
  }
  if (tid < BNODES) {
    int excl = ts[tid] - v;
    int node = n0 + tid;
    float dv = rsqrtf((float)v + 1.0f);
    dinvL[tid] = dv;
    if (node < N_NODES) {
      off[node]  = b * BCAP + excl;
      edeg[node] = v;
      dinv[node] = dv;
    }
    cnt[tid] = excl;
  }
  __syncthreads();

  for (int i = tid; i < m; i += 512) {
    unsigned int p = raw[i];
    int pos = atomicAdd(&cnt[p >> 17], 1);
    if (pos < BCAP) sorted[pos] = (int)(p & SRC_MASK);
  }
  __syncthreads();

  int* out = eSrc + (size_t)b * BCAP;
  for (int i = tid; i < m; i += 512) out[i] = sorted[i];

  // fused layer-1 prescale for this block's node range
  const int rows = min(BNODES, N_NODES - n0);
  for (int i = tid; i < rows * 64; i += 512) {
    int r = i >> 6;
    size_t g = (size_t)(n0 + r) * 64 + (i & 63);
    Xs[g] = f2bf(dinvL[r] * x[g]);
  }
}

// ---------------------------------------------------------------------------
// CSR aggregation v3: one wave per node, 8 edges per uint4 gather, bf16 out.
// Main loop unmasked (full 32-edge batches); single masked tail batch.
// ---------------------------------------------------------------------------
__global__ __launch_bounds__(256) void agg_csr(
    const int* __restrict__ off, const int* __restrict__ edeg,
    const int* __restrict__ eSrc, const unsigned short* __restrict__ Xs,
    const float* __restrict__ dinv, unsigned short* __restrict__ agg) {
  const int wid = (blockIdx.x * 256 + threadIdx.x) >> 6;
  const int lane = threadIdx.x & 63;
  const int grp = lane >> 3, sub = lane & 7;
  if (wid >= N_NODES) return;
  const int s0 = off[wid];
  const int s1 = s0 + edeg[wid];
  const uint4* XsV = (const uint4*)Xs;

  float2 acc[4];
  {
    uint4 u = XsV[(size_t)wid * 8 + sub];     // self loop: only grp 0 adds it
    if (grp != 0) { u.x = 0; u.y = 0; u.z = 0; u.w = 0; }
    acc[0] = bfpair(u.x);
    acc[1] = bfpair(u.y);
    acc[2] = bfpair(u.z);
    acc[3] = bfpair(u.w);
  }

  int e = s0;
  const int eend = s1 - ((s1 - s0) & 31);
  for (; e < eend; e += 32) {                 // unmasked, 4 gathers in flight
    int sa = eSrc[e + grp];
    int sb = eSrc[e + 8 + grp];
    int sc = eSrc[e + 16 + grp];
    int sd = eSrc[e + 24 + grp];
    uint4 ua = XsV[(size_t)sa * 8 + sub];
    uint4 ub = XsV[(size_t)sb * 8 + sub];
    uint4 uc = XsV[(size_t)sc * 8 + sub];
    uint4 ud = XsV[(size_t)sd * 8 + sub];
    addp(acc, ua); addp(acc, ub); addp(acc, uc); addp(acc, ud);
  }
  if (e < s1) {                               // single masked tail batch
    const int lim = s1 - 1;
    int ea = e + grp, eb = e + 8 + grp, ec = e + 16 + grp, ed = e + 24 + grp;
    int sa = eSrc[min(ea, lim)];
    int sb = eSrc[min(eb, lim)];
    int sc = eSrc[min(ec, lim)];
    int sd = eSrc[min(ed, lim)];
    uint4 ua = XsV[(size_t)sa * 8 + sub];
    uint4 ub = XsV[(size_t)sb * 8 + sub];
    uint4 uc = XsV[(size_t)sc * 8 + sub];
    uint4 ud = XsV[(size_t)sd * 8 + sub];
    if (ea > lim) { ua.x = 0; ua.y = 0; ua.z = 0; ua.w = 0; }
    if (eb > lim) { ub.x = 0; ub.y = 0; ub.z = 0; ub.w = 0; }
    if (ec > lim) { uc.x = 0; uc.y = 0; uc.z = 0; uc.w = 0; }
    if (ed > lim) { ud.x = 0; ud.y = 0; ud.z = 0; ud.w = 0; }
    addp(acc, ua); addp(acc, ub); addp(acc, uc); addp(acc, ud);
  }

  #pragma unroll
  for (int mk = 8; mk <= 32; mk <<= 1) {
    #pragma unroll
    for (int i = 0; i < 4; ++i) {
      acc[i].x += __shfl_xor(acc[i].x, mk, 64);
      acc[i].y += __shfl_xor(acc[i].y, mk, 64);
    }
  }

  if (grp == 0) {
    float dt = dinv[wid];
    uint4 o;
    o.x = ((unsigned)f2bf(acc[0].y * dt) << 16) | f2bf(acc[0].x * dt);
    o.y = ((unsigned)f2bf(acc[1].y * dt) << 16) | f2bf(acc[1].x * dt);
    o.z = ((unsigned)f2bf(acc[2].y * dt) << 16) | f2bf(acc[2].x * dt);
    o.w = ((unsigned)f2bf(acc[3].y * dt) << 16) | f2bf(acc[3].x * dt);
    *(uint4*)(agg + (size_t)wid * 64 + sub * 8) = o;
  }
}

// ---------------------------------------------------------------------------
// MFMA GEMM: Yb(bf16)[128-row block] = A(bf16) @ WcB + bc, fused col stats.
// ---------------------------------------------------------------------------
__global__ __launch_bounds__(256) void gemm_stats(
    const unsigned short* __restrict__ A, const unsigned int* __restrict__ WcB,
    const float* __restrict__ bc, unsigned short* __restrict__ Yb,
    float* __restrict__ colsum, float* __restrict__ colsq) {
  const int tid = threadIdx.x;
  const int L = tid & 63, wv = tid >> 6;
  const int quad = L >> 4, l16 = L & 15;

  const bf16x8* Wv = (const bf16x8*)WcB;      // frag f at Wv[f*64 + L]
  bf16x8 bfr[4][2];
  #pragma unroll
  for (int nt = 0; nt < 4; ++nt)
    #pragma unroll
    for (int kh = 0; kh < 2; ++kh)
      bfr[nt][kh] = Wv[(nt * 2 + kh) * 64 + L];
  float bcv[4];
  #pragma unroll
  for (int nt = 0; nt < 4; ++nt) bcv[nt] = bc[nt * 16 + l16];

  const bf16x8* Av = (const bf16x8*)A;
  float psum[4] = {0.f, 0.f, 0.f, 0.f}, psq[4] = {0.f, 0.f, 0.f, 0.f};

  #pragma unroll
  for (int loop = 0; loop < 2; ++loop) {
    const int rowbase = blockIdx.x * 128 + loop * 64 + wv * 16;
    const int m = min(rowbase + l16, N_NODES - 1);
    bf16x8 a0 = Av[(size_t)m * 8 + quad];
    bf16x8 a1 = Av[(size_t)m * 8 + 4 + quad];
    #pragma unroll
    for (int nt = 0; nt < 4; ++nt) {
      f32x4 acc = {0.f, 0.f, 0.f, 0.f};
      acc = __builtin_amdgcn_mfma_f32_16x16x32_bf16(a0, bfr[nt][0], acc, 0, 0, 0);
      acc = __builtin_amdgcn_mfma_f32_16x16x32_bf16(a1, bfr[nt][1], acc, 0, 0, 0);
      #pragma unroll
      for (int r = 0; r < 4; ++r) {
        int row = rowbase + quad * 4 + r;
        if (row < N_NODES) {
          float y = acc[r] + bcv[nt];
          Yb[(size_t)row * 64 + nt * 16 + l16] = f2bf(y);
          psum[nt] += y;
          psq[nt] += y * y;
        }
      }
    }
  }

  #pragma unroll
  for (int nt = 0; nt < 4; ++nt) {
    psum[nt] += __shfl_xor(psum[nt], 16, 64);
    psum[nt] += __shfl_xor(psum[nt], 32, 64);
    psq[nt]  += __shfl_xor(psq[nt], 16, 64);
    psq[nt]  += __shfl_xor(psq[nt], 32, 64);
  }
  __shared__ float rsum[4][64];
  __shared__ float rsq[4][64];
  if (L < 16) {
    #pragma unroll
    for (int nt = 0; nt < 4; ++nt) {
      rsum[wv][nt * 16 + L] = psum[nt];
      rsq[wv][nt * 16 + L]  = psq[nt];
    }
  }
  __syncthreads();
  if (tid < 64) {
    float s = rsum[0][tid] + rsum[1][tid] + rsum[2][tid] + rsum[3][tid];
    float q = rsq[0][tid] + rsq[1][tid] + rsq[2][tid] + rsq[3][tid];
    atomicAdd(&colsum[tid], s);
    atomicAdd(&colsq[tid], q);
  }
}

// ---------------------------------------------------------------------------
// prescale_y (+inline finalize of layer-1 BN):
//   Xs[i][:] = bf16( dinv[i] * relu(Yb*a1 + c1) )   (in place over Yb buffer)
// ---------------------------------------------------------------------------
__global__ __launch_bounds__(256) void prescale_y(
    unsigned short* __restrict__ YbXs, const float* __restrict__ dinv,
    const float* __restrict__ colsum, const float* __restrict__ colsq,
    const float* __restrict__ g, const float* __restrict__ bt) {
  __shared__ float sa[64], sc[64];
  if (threadIdx.x < 64) {
    int j = threadIdx.x;
    float mu = colsum[j] * (1.0f / N_NODES);
    float var = colsq[j] * (1.0f / N_NODES) - mu * mu;
    float s = rsqrtf(var + EPS) * g[j];
    sa[j] = s;
    sc[j] = bt[j] - mu * s;
  }
  __syncthreads();
  int idx = blockIdx.x * blockDim.x + threadIdx.x;
  if (idx < N_NODES * D) {
    int i = idx >> 6, j = idx & 63;
    float y = bf2f(YbXs[idx]);
    YbXs[idx] = f2bf(dinv[i] * fmaxf(fmaf(y, sa[j], sc[j]), 0.f));
  }
}

// ---------------------------------------------------------------------------
// final_norm (+inline finalize of layer-2 BN): out = relu(Yb*a2 + c2), fp32
// ---------------------------------------------------------------------------
__global__ __launch_bounds__(256) void final_norm(
    const unsigned short* __restrict__ Yb, float* __restrict__ out,
    const float* __restrict__ colsum, const float* __restrict__ colsq,
    const float* __restrict__ g, const float* __restrict__ bt) {
  __shared__ float sa[64], sc[64];
  if (threadIdx.x < 64) {
    int j = threadIdx.x;
    float mu = colsum[j] * (1.0f / N_NODES);
    float var = colsq[j] * (1.0f / N_NODES) - mu * mu;
    float s = rsqrtf(var + EPS) * g[j];
    sa[j] = s;
    sc[j] = bt[j] - mu * s;
  }
  __syncthreads();
  int idx = blockIdx.x * blockDim.x + threadIdx.x;
  if (idx < N_NODES * D) {
    int j = idx & 63;
    out[idx] = fmaxf(fmaf(bf2f(Yb[idx]), sa[j], sc[j]), 0.f);
  }
}

extern "C" void kernel_launch(void* const* d_in, const int* in_sizes, int n_in,
                              void* d_out, int out_size, void* d_ws, size_t ws_size,
                              hipStream_t stream) {
  const float* x   = (const float*)d_in[0];
  const int*   src = (const int*)d_in[1];          // edge_index row 0
  const int*   dst = src + N_EDGES;                // edge_index row 1
  const float* W1  = (const float*)d_in[2];
  const float* b1  = (const float*)d_in[3];
  const float* fw1 = (const float*)d_in[4];
  const float* fb1 = (const float*)d_in[5];
  const float* g1  = (const float*)d_in[6];
  const float* bt1 = (const float*)d_in[7];
  const float* W2  = (const float*)d_in[8];
  const float* b2  = (const float*)d_in[9];
  const float* fw2 = (const float*)d_in[10];
  const float* fb2 = (const float*)d_in[11];
  const float* g2  = (const float*)d_in[12];
  const float* bt2 = (const float*)d_in[13];

  float* out = (float*)d_out;                      // N x 64 fp32

  // workspace (~42 MB). stage aliases aggb; Xs doubles as the bf16 Y buffer:
  //   pass2 writes Xs(L1) -> agg1 reads Xs, writes aggb -> gemm1 writes Yb(=Xs)
  //   -> prescale_y converts Yb->Xs(L2) in place -> agg2 -> gemm2 -> final.
  unsigned char* w = (unsigned char*)d_ws;
  unsigned int*   stage = (unsigned int*)w;              // NB_P1*8192 uints
  unsigned short* aggb  = (unsigned short*)w;            // N*64 bf16 (alias)
  size_t ofs = ((size_t)NB_P1 * P1_CHUNK * 4 + 255) & ~(size_t)255;
  float*          dinv  = (float*)(w + ofs);             // N floats
  unsigned short* XsYb  = (unsigned short*)(dinv + N_NODES);          // N*64 bf16
  int*            eSrc  = (int*)(XsYb + (size_t)N_NODES * D);         // NBUCK*BCAP ints
  int*            off   = eSrc + (size_t)NBUCK * BCAP;   // N ints
  int*            edeg  = off + N_NODES;                 // N ints
  unsigned short* tbl   = (unsigned short*)(edeg + N_NODES);          // NB_P1*784 ushort
  unsigned int* WcB1 = (unsigned int*)(tbl + (size_t)NB_P1 * TBL_STRIDE); // 2048
  float* bc1  = (float*)(WcB1 + 2048);             // 64
  unsigned int* WcB2 = (unsigned int*)(bc1 + 64);  // 2048
  float* bc2  = (float*)(WcB2 + 2048);             // 64
  float* sum1 = bc2 + 64;                          // 64  (sum1..sq2 contiguous 256)
  float* sq1  = sum1 + 64;
  float* sum2 = sq1 + 64;
  float* sq2  = sum2 + 64;

  const int nd = N_NODES * D;
  dim3 blk(256);

  combine_weights<<<3, blk, 0, stream>>>(W1, b1, fw1, fb1, W2, b2, fw2, fb2,
                                         WcB1, bc1, WcB2, bc2, sum1);

  // ---- partition: block-local sort -> per-bucket node CSR (+L1 prescale) ----
  pass1_sort<<<NB_P1, 512, 0, stream>>>(src, dst, stage, tbl);
  pass2_sort<<<NBUCK, 512, 0, stream>>>(stage, tbl, eSrc, off, edeg, dinv, x, XsYb);

  // ---- layer 1 ----
  agg_csr<<<(nd + 255) / 256, blk, 0, stream>>>(off, edeg, eSrc, XsYb, dinv, aggb);
  gemm_stats<<<(N_NODES + 127) / 128, blk, 0, stream>>>(aggb, WcB1, bc1, XsYb, sum1, sq1);

  // ---- layer 2 ----
  prescale_y<<<(nd + 255) / 256, blk, 0, stream>>>(XsYb, dinv, sum1, sq1, g1, bt1);
  agg_csr<<<(nd + 255) / 256, blk, 0, stream>>>(off, edeg, eSrc, XsYb, dinv, aggb);
  gemm_stats<<<(N_NODES + 127) / 128, blk, 0, stream>>>(aggb, WcB2, bc2, XsYb, sum2, sq2);

  final_norm<<<(nd + 255) / 256, blk, 0, stream>>>(XsYb, out, sum2, sq2, g2, bt2);
}